// Round 16
// baseline (881.933 us; speedup 1.0000x reference)
//
#include <hip/hip_runtime.h>
#include <hip/hip_bf16.h>

#define GLOBAL_AS __attribute__((address_space(1)))
#define LDS_AS    __attribute__((address_space(3)))

typedef __attribute__((ext_vector_type(4))) float  f32x4;
typedef __attribute__((ext_vector_type(8))) short  bf16x8;

static constexpr int   H      = 128;
static constexpr float BN_EPS = 1e-5f;

__device__ __forceinline__ float bf2f(ushort u) {
  union { unsigned u; float f; } x; x.u = ((unsigned)u) << 16; return x.f;
}
__device__ __forceinline__ ushort f2bf(float f) {
  union { float f; unsigned u; } x; x.f = f;
  unsigned r = x.u + 0x7fffu + ((x.u >> 16) & 1u);
  return (ushort)(r >> 16);
}

// ---------------- unified weight folding (single launch) ----------------
__device__ __forceinline__ void fold_pack_one(const float* __restrict__ W,
                                              const float* __restrict__ b,
                                              const float* __restrict__ bn,
                                              int K, int NOUT, int idx,
                                              ushort* __restrict__ Wp,
                                              float* __restrict__ bout) {
  int o = idx / K, k = idx - o * K;
  float scale = 1.0f, shift = 0.0f;
  if (bn != nullptr) {
    float g = bn[o], be = bn[NOUT + o], m = bn[2 * NOUT + o], v = bn[3 * NOUT + o];
    scale = g * rsqrtf(v + BN_EPS);
    shift = be - m * scale;
  }
  int gt = o >> 4, lr = o & 15, ks = k >> 5, lk = (k >> 3) & 3, e = k & 7;
  size_t pos = ((((size_t)gt * (K / 32) + ks) * 64) + lk * 16 + lr) * 8 + e;
  Wp[pos] = f2bf(W[(size_t)k * NOUT + o] * scale);
  if (k == 0) bout[o] = b[o] * scale + shift;
}

__device__ __forceinline__ void fold_f32_one(const float* __restrict__ W,
                                             const float* __restrict__ b,
                                             const float* __restrict__ bn,
                                             int K, int NOUT, int idx,
                                             float* __restrict__ Wt,
                                             float* __restrict__ bout) {
  int o = idx / K, k = idx - o * K;
  float scale = 1.0f, shift = 0.0f;
  if (bn != nullptr) {
    float g = bn[o], be = bn[NOUT + o], m = bn[2 * NOUT + o], v = bn[3 * NOUT + o];
    scale = g * rsqrtf(v + BN_EPS);
    shift = be - m * scale;
  }
  Wt[(size_t)o * K + k] = W[(size_t)k * NOUT + o] * scale;
  if (k == 0) bout[o] = b[o] * scale + shift;
}

__global__ __launch_bounds__(256) void fold_all_kernel(
    const float* __restrict__ in_W, const float* __restrict__ in_b, const float* __restrict__ in_bn,
    const float* __restrict__ W1, const float* __restrict__ b1, const float* __restrict__ bn1,
    const float* __restrict__ W2, const float* __restrict__ b2, const float* __restrict__ bn2,
    const float* __restrict__ W3, const float* __restrict__ b3, const float* __restrict__ nbn,
    const float* __restrict__ cW1, const float* __restrict__ cb1, const float* __restrict__ cbn1,
    const float* __restrict__ cW2, const float* __restrict__ cb2, const float* __restrict__ cbn2,
    const float* __restrict__ fW, const float* __restrict__ fb,
    ushort* __restrict__ wIn, float* __restrict__ bIn,
    ushort* __restrict__ w1f, float* __restrict__ b1f,
    ushort* __restrict__ w2f, float* __restrict__ b2f,
    ushort* __restrict__ w3f, float* __restrict__ b3f,
    float* __restrict__ cw1f, float* __restrict__ cb1f,
    float* __restrict__ cw2f, float* __restrict__ cb2f,
    float* __restrict__ cw3f, float* __restrict__ cb3f) {
  int idx = blockIdx.x * 256 + threadIdx.x;
  if (idx < 16384) {
    fold_pack_one(in_W, in_b, in_bn, 128, 128, idx, wIn, bIn);
    return;
  }
  idx -= 16384;
  if (idx < 5 * 180224) {
    int layer = idx / 180224;
    int r = idx - layer * 180224;
    if (r < 49152) {
      fold_pack_one(W1 + (size_t)layer * 49152, b1 + (size_t)layer * 384,
                    bn1 + (size_t)layer * 4 * 384, 128, 384, r,
                    w1f + (size_t)layer * 49152, b1f + (size_t)layer * 384);
    } else if (r < 147456) {
      fold_pack_one(W2 + (size_t)layer * 98304, b2 + (size_t)layer * 256,
                    bn2 + (size_t)layer * 4 * 256, 384, 256, r - 49152,
                    w2f + (size_t)layer * 98304, b2f + (size_t)layer * 256);
    } else {
      fold_pack_one(W3 + (size_t)layer * 32768, b3 + (size_t)layer * 128,
                    nbn + (size_t)layer * 4 * 128, 256, 128, r - 147456,
                    w3f + (size_t)layer * 32768, b3f + (size_t)layer * 128);
    }
    return;
  }
  idx -= 5 * 180224;
  if (idx < 49152) { fold_f32_one(cW1, cb1, cbn1, 384, 128, idx, cw1f, cb1f); return; }
  idx -= 49152;
  if (idx < 8192)  { fold_f32_one(cW2, cb2, cbn2, 128, 64, idx, cw2f, cb2f); return; }
  idx -= 8192;
  if (idx < 384)   { fold_f32_one(fW, fb, nullptr, 64, 6, idx, cw3f, cb3f); return; }
}

// ---------------- fp32 -> bf16 convert (x) ----------------
__global__ void cvt4_kernel(const float* __restrict__ x, ushort* __restrict__ xb, int n4) {
  int i = blockIdx.x * blockDim.x + threadIdx.x;
  if (i >= n4) return;
  float4 v = ((const float4*)x)[i];
  ushort4 o; o.x = f2bf(v.x); o.y = f2bf(v.y); o.z = f2bf(v.z); o.w = f2bf(v.w);
  ((ushort4*)xb)[i] = o;
}

// ---------------- CSR build ----------------
__global__ void hist_kernel(const int* __restrict__ idx, int n, int* __restrict__ cnt) {
  int i = blockIdx.x * blockDim.x + threadIdx.x;
  if (i < n) atomicAdd(&cnt[idx[i]], 1);
}

__global__ void gbound_kernel(const int* __restrict__ batch, int N, int G,
                              int* __restrict__ gptr) {
  int i = blockIdx.x * blockDim.x + threadIdx.x;
  if (i >= N) return;
  int b = batch[i];
  int prev = (i == 0) ? -1 : batch[i - 1];
  for (int g = prev + 1; g <= b; ++g) gptr[g] = i;
  if (i == N - 1) for (int g = b + 1; g <= G; ++g) gptr[g] = N;
}

__global__ void block_sum_kernel(const int* __restrict__ v, int n, int* __restrict__ bsum) {
  __shared__ int s[256];
  int i = blockIdx.x * 256 + threadIdx.x;
  int x = (i < n) ? v[i] : 0;
  s[threadIdx.x] = x; __syncthreads();
  for (int off = 128; off > 0; off >>= 1) {
    if (threadIdx.x < (unsigned)off) s[threadIdx.x] += s[threadIdx.x + off];
    __syncthreads();
  }
  if (threadIdx.x == 0) bsum[blockIdx.x] = s[0];
}

__global__ void scan_block_kernel(int* __restrict__ bsum, int nb,
                                  int* __restrict__ last_out, int total) {
  __shared__ int s[256];
  __shared__ int carry;
  if (threadIdx.x == 0) carry = 0;
  __syncthreads();
  for (int base = 0; base < nb; base += 256) {
    int i = base + threadIdx.x;
    int x = (i < nb) ? bsum[i] : 0;
    s[threadIdx.x] = x; __syncthreads();
    for (int off = 1; off < 256; off <<= 1) {
      int add = (threadIdx.x >= (unsigned)off) ? s[threadIdx.x - off] : 0;
      __syncthreads();
      s[threadIdx.x] += add;
      __syncthreads();
    }
    if (i < nb) bsum[i] = carry + s[threadIdx.x] - x;   // exclusive
    __syncthreads();
    if (threadIdx.x == 0) carry += s[255];
    __syncthreads();
  }
  if (last_out && threadIdx.x == 0) *last_out = total;
}

__global__ void scan_final_kernel(const int* __restrict__ v, int n, const int* __restrict__ bsum,
                                  int* __restrict__ rowptr, int* __restrict__ cursor) {
  __shared__ int s[256];
  int i = blockIdx.x * 256 + threadIdx.x;
  int x = (i < n) ? v[i] : 0;
  s[threadIdx.x] = x; __syncthreads();
  for (int off = 1; off < 256; off <<= 1) {
    int add = (threadIdx.x >= (unsigned)off) ? s[threadIdx.x - off] : 0;
    __syncthreads();
    s[threadIdx.x] += add;
    __syncthreads();
  }
  if (i < n) {
    int excl = bsum[blockIdx.x] + s[threadIdx.x] - x;
    rowptr[i] = excl;
    if (cursor) cursor[i] = excl;
  }
}

// dst-range-partitioned scatter; NONTEMPORAL edge loads keep the streaming src/dst
// out of L2 so each partition's col window + cursors stay resident (round-15 profile:
// 80MB WRITE for 6.4MB payload = window eviction by the dst stream).
__global__ __launch_bounds__(256) void scatter_part_kernel(
    const int* __restrict__ src, const int* __restrict__ dst, int E,
    int* __restrict__ cursor, int* __restrict__ col, int npp) {
  const int part  = blockIdx.x & 7;
  const int chunk = blockIdx.x >> 3;
  const int lo = part * npp, hi = lo + npp;
  const int i0 = chunk * 1024 + threadIdx.x * 4;
  if (i0 + 3 < E) {
    int d0 = __builtin_nontemporal_load(dst + i0 + 0);
    int d1 = __builtin_nontemporal_load(dst + i0 + 1);
    int d2 = __builtin_nontemporal_load(dst + i0 + 2);
    int d3 = __builtin_nontemporal_load(dst + i0 + 3);
    if (d0 >= lo && d0 < hi) { int p = atomicAdd(&cursor[d0], 1); col[p] = __builtin_nontemporal_load(src + i0 + 0); }
    if (d1 >= lo && d1 < hi) { int p = atomicAdd(&cursor[d1], 1); col[p] = __builtin_nontemporal_load(src + i0 + 1); }
    if (d2 >= lo && d2 < hi) { int p = atomicAdd(&cursor[d2], 1); col[p] = __builtin_nontemporal_load(src + i0 + 2); }
    if (d3 >= lo && d3 < hi) { int p = atomicAdd(&cursor[d3], 1); col[p] = __builtin_nontemporal_load(src + i0 + 3); }
  } else {
    for (int u = 0; u < 4; ++u) {
      int i = i0 + u;
      if (i < E) {
        int d = dst[i];
        if (d >= lo && d < hi) { int p = atomicAdd(&cursor[d], 1); col[p] = src[i]; }
      }
    }
  }
}

// ---------------- GIN aggregation (round-12 proven: 4-deep gather unroll) --------------
__global__ __launch_bounds__(256) void agg_kernel(
    const ushort* __restrict__ hb,
    const int* __restrict__ rowptr, const int* __restrict__ col,
    const float* __restrict__ eps_g, int layer,
    ushort* __restrict__ z, int n) {
  int node = blockIdx.x * 4 + (threadIdx.x >> 6);
  if (node >= n) return;
  const int lane = threadIdx.x & 63;
  const int l16  = lane & 15;
  const int grp  = lane >> 4;
  const int s = rowptr[node], e = rowptr[node + 1];
  float a0 = 0.f, a1 = 0.f, a2 = 0.f, a3 = 0.f, a4 = 0.f, a5 = 0.f, a6 = 0.f, a7 = 0.f;
  const size_t co = (size_t)l16 * 8;
  int j = s + grp;
  for (; j + 12 < e; j += 16) {
    int i0 = col[j], i1 = col[j + 4], i2 = col[j + 8], i3 = col[j + 12];
    bf16x8 v0 = *(const bf16x8*)(hb + (size_t)i0 * H + co);
    bf16x8 v1 = *(const bf16x8*)(hb + (size_t)i1 * H + co);
    bf16x8 v2 = *(const bf16x8*)(hb + (size_t)i2 * H + co);
    bf16x8 v3 = *(const bf16x8*)(hb + (size_t)i3 * H + co);
    a0 += (bf2f((ushort)v0[0]) + bf2f((ushort)v1[0])) + (bf2f((ushort)v2[0]) + bf2f((ushort)v3[0]));
    a1 += (bf2f((ushort)v0[1]) + bf2f((ushort)v1[1])) + (bf2f((ushort)v2[1]) + bf2f((ushort)v3[1]));
    a2 += (bf2f((ushort)v0[2]) + bf2f((ushort)v1[2])) + (bf2f((ushort)v2[2]) + bf2f((ushort)v3[2]));
    a3 += (bf2f((ushort)v0[3]) + bf2f((ushort)v1[3])) + (bf2f((ushort)v2[3]) + bf2f((ushort)v3[3]));
    a4 += (bf2f((ushort)v0[4]) + bf2f((ushort)v1[4])) + (bf2f((ushort)v2[4]) + bf2f((ushort)v3[4]));
    a5 += (bf2f((ushort)v0[5]) + bf2f((ushort)v1[5])) + (bf2f((ushort)v2[5]) + bf2f((ushort)v3[5]));
    a6 += (bf2f((ushort)v0[6]) + bf2f((ushort)v1[6])) + (bf2f((ushort)v2[6]) + bf2f((ushort)v3[6]));
    a7 += (bf2f((ushort)v0[7]) + bf2f((ushort)v1[7])) + (bf2f((ushort)v2[7]) + bf2f((ushort)v3[7]));
  }
  for (; j + 4 < e; j += 8) {
    int i0 = col[j], i1 = col[j + 4];
    bf16x8 v0 = *(const bf16x8*)(hb + (size_t)i0 * H + co);
    bf16x8 v1 = *(const bf16x8*)(hb + (size_t)i1 * H + co);
    a0 += bf2f((ushort)v0[0]) + bf2f((ushort)v1[0]);
    a1 += bf2f((ushort)v0[1]) + bf2f((ushort)v1[1]);
    a2 += bf2f((ushort)v0[2]) + bf2f((ushort)v1[2]);
    a3 += bf2f((ushort)v0[3]) + bf2f((ushort)v1[3]);
    a4 += bf2f((ushort)v0[4]) + bf2f((ushort)v1[4]);
    a5 += bf2f((ushort)v0[5]) + bf2f((ushort)v1[5]);
    a6 += bf2f((ushort)v0[6]) + bf2f((ushort)v1[6]);
    a7 += bf2f((ushort)v0[7]) + bf2f((ushort)v1[7]);
  }
  if (j < e) {
    bf16x8 v0 = *(const bf16x8*)(hb + (size_t)col[j] * H + co);
    a0 += bf2f((ushort)v0[0]); a1 += bf2f((ushort)v0[1]);
    a2 += bf2f((ushort)v0[2]); a3 += bf2f((ushort)v0[3]);
    a4 += bf2f((ushort)v0[4]); a5 += bf2f((ushort)v0[5]);
    a6 += bf2f((ushort)v0[6]); a7 += bf2f((ushort)v0[7]);
  }
  a0 += __shfl_xor(a0, 16); a0 += __shfl_xor(a0, 32);
  a1 += __shfl_xor(a1, 16); a1 += __shfl_xor(a1, 32);
  a2 += __shfl_xor(a2, 16); a2 += __shfl_xor(a2, 32);
  a3 += __shfl_xor(a3, 16); a3 += __shfl_xor(a3, 32);
  a4 += __shfl_xor(a4, 16); a4 += __shfl_xor(a4, 32);
  a5 += __shfl_xor(a5, 16); a5 += __shfl_xor(a5, 32);
  a6 += __shfl_xor(a6, 16); a6 += __shfl_xor(a6, 32);
  a7 += __shfl_xor(a7, 16); a7 += __shfl_xor(a7, 32);
  float sx, sy;
  if      (grp == 0) { sx = a0; sy = a1; }
  else if (grp == 1) { sx = a2; sy = a3; }
  else if (grp == 2) { sx = a4; sy = a5; }
  else               { sx = a6; sy = a7; }
  const int c0 = l16 * 8 + grp * 2;
  float ep = 1.0f + eps_g[layer];
  ushort2 hs = *(const ushort2*)(hb + (size_t)node * H + c0);
  ushort2 o;
  o.x = f2bf(ep * bf2f(hs.x) + sx);
  o.y = f2bf(ep * bf2f(hs.y) + sy);
  *(ushort2*)(z + (size_t)node * H + c0) = o;
}

// ---------------- input projection GEMM (M=64, packed weights) ----------------
template<int K, int NOUT>
__global__ __launch_bounds__(256) void gemm_kernel(
    const ushort* __restrict__ A, const ushort* __restrict__ Wp,
    const float* __restrict__ bias,
    ushort* __restrict__ outb, float* __restrict__ hf) {
  constexpr int ROWB = 2 * K;
  __shared__ __align__(16) char lds[64 * ROWB];
  const int t = threadIdx.x;
  const long row0 = (long)blockIdx.x * 64;
  const char* Ab = (const char*)(A + (size_t)row0 * K);

  constexpr int ITERS = (64 * ROWB) / (256 * 16);
#pragma unroll
  for (int it = 0; it < ITERS; ++it) {
    int ob = (it * 256 + t) * 16;
    int r = ob / ROWB;
    int c = ob - r * ROWB;
    int sb = r * ROWB + (c ^ ((r & 7) << 4));
    __builtin_amdgcn_global_load_lds((const GLOBAL_AS void*)(Ab + sb),
                                     (LDS_AS void*)(lds + ob), 16, 0, 0);
  }
  __syncthreads();

  const int l  = t & 63;
  const int w  = t >> 6;
  const int lr = l & 15;
  const int lk = l >> 4;
  constexpr int CPW = NOUT / 4;
  constexpr int NCT = CPW / 16;

  for (int ct = 0; ct < NCT; ++ct) {
    const int colbase = w * CPW + ct * 16;
    const ushort* tb = Wp + ((size_t)(colbase >> 4) * (K / 32)) * 512;
    f32x4 acc[4] = {};
#pragma unroll
    for (int ks = 0; ks < K / 32; ++ks) {
      bf16x8 bfr = *(const bf16x8*)(tb + ks * 512 + l * 8);
#pragma unroll
      for (int rt = 0; rt < 4; ++rt) {
        const int rr = rt * 16 + lr;
        const int kb = ks * 64 + lk * 16;
        bf16x8 afr = *(const bf16x8*)(lds + rr * ROWB + (kb ^ ((rr & 7) << 4)));
        acc[rt] = __builtin_amdgcn_mfma_f32_16x16x32_bf16(bfr, afr, acc[rt], 0, 0, 0);
      }
    }
    const int c0 = colbase + lk * 4;
    const float b0 = bias[c0], b1 = bias[c0 + 1], b2 = bias[c0 + 2], b3 = bias[c0 + 3];
#pragma unroll
    for (int rt = 0; rt < 4; ++rt) {
      const long grow = row0 + rt * 16 + lr;
      float v0 = fmaxf(acc[rt][0] + b0, 0.f);
      float v1 = fmaxf(acc[rt][1] + b1, 0.f);
      float v2 = fmaxf(acc[rt][2] + b2, 0.f);
      float v3 = fmaxf(acc[rt][3] + b3, 0.f);
      *(float4*)(hf + grow * H + c0) = make_float4(v0, v1, v2, v3);
      ushort4 sv; sv.x = f2bf(v0); sv.y = f2bf(v1); sv.z = f2bf(v2); sv.w = f2bf(v3);
      *(ushort4*)(outb + grow * NOUT + c0) = sv;
    }
  }
}

// ---------------- fused per-layer MLP (M=128, 1024 threads / 16 waves, 128KB LDS) -----
// 2 row-halves (wh) x 8 col-groups (wc); per-wave schedule identical to the proven
// round-14 wave. Weight L2 stream halves again (782 blocks x 352KB = 275MB).
// 1 block/CU x 16 waves = 16 waves/CU (same as round-14's 2x8).
// LDS: t1 [0,96K) rows 768B; zz [96K,128K) rows 256B; t2 [64K,128K) rows 512B
// (overlays t1-top + zz after ALL stage-2 reads complete).
template<int HMODE>  // 1: write h (no residual), 2: h += old
__global__ __launch_bounds__(1024, 4) void mlp_fused_kernel(
    const ushort* __restrict__ zin,
    const ushort* __restrict__ w1, const float* __restrict__ bb1,
    const ushort* __restrict__ w2, const float* __restrict__ bb2,
    const ushort* __restrict__ w3, const float* __restrict__ bb3,
    ushort* __restrict__ hb, float* __restrict__ hf) {
  __shared__ __align__(16) char lds[128 * 1024];
  char* t1 = lds;                // [128][768B]
  char* zz = lds + 96 * 1024;    // [128][256B]
  char* t2 = lds + 64 * 1024;    // [128][512B], overlay after stage-2 reads

  const int t = threadIdx.x;
  const long row0 = (long)blockIdx.x * 128;
  const char* Ab = (const char*)(zin + (size_t)row0 * 128);

  // stage z tile (128 x 128 bf16 = 32KB): 1024 thr x 16B = 16KB/iter -> 2 iters
#pragma unroll
  for (int it = 0; it < 2; ++it) {
    int ob = (it * 1024 + t) * 16;
    int r = ob >> 8;
    int c = ob & 255;
    int sb = r * 256 + (c ^ ((r & 7) << 4));
    __builtin_amdgcn_global_load_lds((const GLOBAL_AS void*)(Ab + sb),
                                     (LDS_AS void*)(zz + ob), 16, 0, 0);
  }
  __syncthreads();

  const int l  = t & 63;
  const int w  = t >> 6;     // 0..15
  const int wh = w >> 3;     // row half 0/1
  const int wc = w & 7;      // col group 0..7
  const int lr = l & 15;
  const int lk = l >> 4;
  const int rbase = wh * 64;

  // ---- stage 1: t1 = relu(z @ w1^T + b1); cols [wc*48,+48), rows [wh*64,+64)
  {
    f32x4 acc[3][4] = {};
#pragma unroll
    for (int ks = 0; ks < 4; ++ks) {
      bf16x8 afr[4];
#pragma unroll
      for (int rt = 0; rt < 4; ++rt) {
        const int rr = rbase + rt * 16 + lr;
        afr[rt] = *(const bf16x8*)(zz + rr * 256 + ((ks * 64 + lk * 16) ^ ((rr & 7) << 4)));
      }
#pragma unroll
      for (int ct = 0; ct < 3; ++ct) {
        bf16x8 bfr = *(const bf16x8*)(w1 + ((size_t)(wc * 3 + ct) * 4 + ks) * 512 + l * 8);
#pragma unroll
        for (int rt = 0; rt < 4; ++rt)
          acc[ct][rt] = __builtin_amdgcn_mfma_f32_16x16x32_bf16(bfr, afr[rt], acc[ct][rt], 0, 0, 0);
      }
    }
#pragma unroll
    for (int ct = 0; ct < 3; ++ct) {
      const int c0 = wc * 48 + ct * 16 + lk * 4;
      const float b0 = bb1[c0], b1 = bb1[c0 + 1], b2 = bb1[c0 + 2], b3 = bb1[c0 + 3];
#pragma unroll
      for (int rt = 0; rt < 4; ++rt) {
        const int rr = rbase + rt * 16 + lr;
        ushort4 sv;
        sv.x = f2bf(fmaxf(acc[ct][rt][0] + b0, 0.f));
        sv.y = f2bf(fmaxf(acc[ct][rt][1] + b1, 0.f));
        sv.z = f2bf(fmaxf(acc[ct][rt][2] + b2, 0.f));
        sv.w = f2bf(fmaxf(acc[ct][rt][3] + b3, 0.f));
        *(ushort4*)(t1 + rr * 768 + ((c0 * 2) ^ ((rr & 7) << 4))) = sv;
      }
    }
  }
  __syncthreads();

  // ---- stage 2: t2 = relu(t1 @ w2^T + b2); cols [wc*32,+32), K=384
  {
    f32x4 acc[2][4] = {};
#pragma unroll
    for (int ks = 0; ks < 12; ++ks) {
      bf16x8 afr[4];
#pragma unroll
      for (int rt = 0; rt < 4; ++rt) {
        const int rr = rbase + rt * 16 + lr;
        afr[rt] = *(const bf16x8*)(t1 + rr * 768 + ((ks * 64 + lk * 16) ^ ((rr & 7) << 4)));
      }
#pragma unroll
      for (int ct = 0; ct < 2; ++ct) {
        bf16x8 bfr = *(const bf16x8*)(w2 + ((size_t)(wc * 2 + ct) * 12 + ks) * 512 + l * 8);
#pragma unroll
        for (int rt = 0; rt < 4; ++rt)
          acc[ct][rt] = __builtin_amdgcn_mfma_f32_16x16x32_bf16(bfr, afr[rt], acc[ct][rt], 0, 0, 0);
      }
    }
    __syncthreads();   // ALL t1/zz reads done; t2 may overlay [64K,128K)
#pragma unroll
    for (int ct = 0; ct < 2; ++ct) {
      const int c0 = wc * 32 + ct * 16 + lk * 4;
      const float b0 = bb2[c0], b1 = bb2[c0 + 1], b2 = bb2[c0 + 2], b3 = bb2[c0 + 3];
#pragma unroll
      for (int rt = 0; rt < 4; ++rt) {
        const int rr = rbase + rt * 16 + lr;
        ushort4 sv;
        sv.x = f2bf(fmaxf(acc[ct][rt][0] + b0, 0.f));
        sv.y = f2bf(fmaxf(acc[ct][rt][1] + b1, 0.f));
        sv.z = f2bf(fmaxf(acc[ct][rt][2] + b2, 0.f));
        sv.w = f2bf(fmaxf(acc[ct][rt][3] + b3, 0.f));
        *(ushort4*)(t2 + rr * 512 + ((c0 * 2) ^ ((rr & 7) << 4))) = sv;
      }
    }
  }
  __syncthreads();

  // ---- stage 3: h = [residual +] relu(t2 @ w3^T + b3); cols [wc*16,+16)
  {
    f32x4 acc[4] = {};
#pragma unroll
    for (int ks = 0; ks < 8; ++ks) {
      bf16x8 afr[4];
#pragma unroll
      for (int rt = 0; rt < 4; ++rt) {
        const int rr = rbase + rt * 16 + lr;
        afr[rt] = *(const bf16x8*)(t2 + rr * 512 + ((ks * 64 + lk * 16) ^ ((rr & 7) << 4)));
      }
      bf16x8 bfr = *(const bf16x8*)(w3 + ((size_t)wc * 8 + ks) * 512 + l * 8);
#pragma unroll
      for (int rt = 0; rt < 4; ++rt)
        acc[rt] = __builtin_amdgcn_mfma_f32_16x16x32_bf16(bfr, afr[rt], acc[rt], 0, 0, 0);
    }
    const int c0 = wc * 16 + lk * 4;
    const float b0 = bb3[c0], b1 = bb3[c0 + 1], b2 = bb3[c0 + 2], b3v = bb3[c0 + 3];
#pragma unroll
    for (int rt = 0; rt < 4; ++rt) {
      const long grow = row0 + rbase + rt * 16 + lr;
      float v0 = fmaxf(acc[rt][0] + b0, 0.f);
      float v1 = fmaxf(acc[rt][1] + b1, 0.f);
      float v2 = fmaxf(acc[rt][2] + b2, 0.f);
      float v3 = fmaxf(acc[rt][3] + b3v, 0.f);
      float4* hp = (float4*)(hf + grow * H + c0);
      if (HMODE == 2) {
        float4 o = *hp;
        v0 += o.x; v1 += o.y; v2 += o.z; v3 += o.w;
      }
      *hp = make_float4(v0, v1, v2, v3);
      ushort4 sv; sv.x = f2bf(v0); sv.y = f2bf(v1); sv.z = f2bf(v2); sv.w = f2bf(v3);
      *(ushort4*)(hb + grow * H + c0) = sv;
    }
  }
}

// ---------------- readout: sum / mean / max per graph (round-15 proven) ----------------
__global__ __launch_bounds__(1024) void readout_kernel(const float* __restrict__ hf,
                                                       const int* __restrict__ gptr,
                                                       float* __restrict__ g) {
  __shared__ float ssum[8][128];
  __shared__ float smax[8][128];
  const int gi  = blockIdx.x;
  const int t   = threadIdx.x;
  const int grp = t >> 7;      // 0..7
  const int c   = t & 127;
  const int s = gptr[gi], e = gptr[gi + 1];
  float sum = 0.f, mx = -INFINITY;
  for (int n = s + grp; n < e; n += 8) {
    float v = hf[(size_t)n * H + c];
    sum += v; mx = fmaxf(mx, v);
  }
  ssum[grp][c] = sum;
  smax[grp][c] = mx;
  __syncthreads();
  if (t < 128) {
    float s0 = 0.f, m0 = -INFINITY;
#pragma unroll
    for (int k = 0; k < 8; ++k) { s0 += ssum[k][t]; m0 = fmaxf(m0, smax[k][t]); }
    const int cnt = e - s;
    g[gi * 384 + t]       = s0;
    g[gi * 384 + 128 + t] = s0 / fmaxf((float)cnt, 1.f);
    g[gi * 384 + 256 + t] = (cnt > 0) ? m0 : 0.f;
  }
}

// ---------------- classifier head ----------------
__global__ __launch_bounds__(128) void classifier_kernel(
    const float* __restrict__ g,
    const float* __restrict__ W1, const float* __restrict__ b1,
    const float* __restrict__ W2, const float* __restrict__ b2,
    const float* __restrict__ W3, const float* __restrict__ b3,
    float* __restrict__ out) {
  __shared__ float row[384];
  __shared__ float f1[128];
  __shared__ float f2s[64];
  int gi = blockIdx.x, t = threadIdx.x;
  for (int i = t; i < 384; i += 128) row[i] = g[gi * 384 + i];
  __syncthreads();
  float a = b1[t];
  for (int k = 0; k < 384; ++k) a += row[k] * W1[t * 384 + k];
  f1[t] = fmaxf(a, 0.f);
  __syncthreads();
  if (t < 64) {
    float a2 = b2[t];
    for (int k = 0; k < 128; ++k) a2 += f1[k] * W2[t * 128 + k];
    f2s[t] = fmaxf(a2, 0.f);
  }
  __syncthreads();
  if (t < 6) {
    float a3 = b3[t];
    for (int k = 0; k < 64; ++k) a3 += f2s[k] * W3[t * 64 + k];
    out[gi * 6 + t] = a3;
  }
}

// ---------------- launcher ----------------
extern "C" void kernel_launch(void* const* d_in, const int* in_sizes, int n_in,
                              void* d_out, int out_size, void* d_ws, size_t ws_size,
                              hipStream_t stream) {
  (void)n_in; (void)ws_size;
  const float* x     = (const float*)d_in[0];
  const int*   eidx  = (const int*)d_in[1];
  const int*   batch = (const int*)d_in[2];
  const float* in_W  = (const float*)d_in[3];
  const float* in_b  = (const float*)d_in[4];
  const float* in_bn = (const float*)d_in[5];
  const float* W1    = (const float*)d_in[6];
  const float* b1    = (const float*)d_in[7];
  const float* bn1   = (const float*)d_in[8];
  const float* W2    = (const float*)d_in[9];
  const float* b2    = (const float*)d_in[10];
  const float* bn2   = (const float*)d_in[11];
  const float* W3    = (const float*)d_in[12];
  const float* b3    = (const float*)d_in[13];
  const float* eps_g = (const float*)d_in[14];
  const float* nbn   = (const float*)d_in[15];
  const float* cW1   = (const float*)d_in[16];
  const float* cb1   = (const float*)d_in[17];
  const float* cbn1  = (const float*)d_in[18];
  const float* cW2   = (const float*)d_in[19];
  const float* cb2   = (const float*)d_in[20];
  const float* cbn2  = (const float*)d_in[21];
  const float* fW    = (const float*)d_in[22];
  const float* fb    = (const float*)d_in[23];

  const int N  = in_sizes[0] / 128;
  const int E  = in_sizes[1] / 2;
  const int G  = out_size / 6;
  const int Mp = ((N + 127) / 128) * 128;   // pad to M=128 tile for the fused MLP
  const int gblocks = Mp / 64;              // input projection (M=64)
  const int mblocks = Mp / 128;             // fused MLP (M=128)
  const int npp = (N + 7) / 8;              // nodes per scatter partition
  const int nchunks = (E + 1023) / 1024;    // edge chunks of 1024

  char* p = (char*)d_ws;
  auto alloc = [&](size_t bytes) -> char* {
    char* r = p; p += (bytes + 255) & ~(size_t)255; return r;
  };
  ushort* hb     = (ushort*)alloc((size_t)Mp * H * 2);
  ushort* zb     = (ushort*)alloc((size_t)Mp * H * 2);
  ushort* xb     = (ushort*)alloc((size_t)Mp * H * 2);
  float*  hf     = (float*)alloc((size_t)Mp * H * 4);
  int*    deg    = (int*)alloc((size_t)N * 4);
  int*    rowptr = (int*)alloc((size_t)(N + 1) * 4);
  int*    cursor = (int*)alloc((size_t)N * 4);
  int*    colx   = (int*)alloc((size_t)E * 4);
  int*    bsum   = (int*)alloc(4096);
  int*    gptr   = (int*)alloc((size_t)(G + 1) * 4);
  float*  gbuf   = (float*)alloc((size_t)G * 384 * 4);
  ushort* wIn    = (ushort*)alloc(128 * 128 * 2);
  float*  bIn    = (float*)alloc(128 * 4);
  ushort* w1f    = (ushort*)alloc((size_t)5 * 384 * 128 * 2);
  float*  b1f    = (float*)alloc((size_t)5 * 384 * 4);
  ushort* w2f    = (ushort*)alloc((size_t)5 * 256 * 384 * 2);
  float*  b2f    = (float*)alloc((size_t)5 * 256 * 4);
  ushort* w3f    = (ushort*)alloc((size_t)5 * 128 * 256 * 2);
  float*  b3f    = (float*)alloc((size_t)5 * 128 * 4);
  float*  cw1f   = (float*)alloc(128 * 384 * 4);
  float*  cb1f   = (float*)alloc(128 * 4);
  float*  cw2f   = (float*)alloc(64 * 128 * 4);
  float*  cb2f   = (float*)alloc(64 * 4);
  float*  cw3f   = (float*)alloc(6 * 64 * 4);
  float*  cb3f   = (float*)alloc(6 * 4);

  // ---- weight folding: ONE launch for all 22 matrices ----
  const int fold_total = 16384 + 5 * 180224 + 49152 + 8192 + 384;
  fold_all_kernel<<<(fold_total + 255) / 256, 256, 0, stream>>>(
      in_W, in_b, in_bn, W1, b1, bn1, W2, b2, bn2, W3, b3, nbn,
      cW1, cb1, cbn1, cW2, cb2, cbn2, fW, fb,
      wIn, bIn, w1f, b1f, w2f, b2f, w3f, b3f,
      cw1f, cb1f, cw2f, cb2f, cw3f, cb3f);

  // ---- x -> bf16 ----
  cvt4_kernel<<<(N * 128 / 4 + 255) / 256, 256, 0, stream>>>(x, xb, N * 128 / 4);

  // ---- CSR build (partitioned scatter) + graph ranges (sorted-batch boundaries) ----
  hipMemsetAsync(deg, 0, (size_t)N * 4, stream);
  hist_kernel<<<(E + 255) / 256, 256, 0, stream>>>(eidx + E, E, deg);
  gbound_kernel<<<(N + 255) / 256, 256, 0, stream>>>(batch, N, G, gptr);
  const int nb = (N + 255) / 256;
  block_sum_kernel<<<nb, 256, 0, stream>>>(deg, N, bsum);
  scan_block_kernel<<<1, 256, 0, stream>>>(bsum, nb, rowptr + N, E);
  scan_final_kernel<<<nb, 256, 0, stream>>>(deg, N, bsum, rowptr, cursor);
  scatter_part_kernel<<<nchunks * 8, 256, 0, stream>>>(eidx, eidx + E, E, cursor, colx, npp);

  // ---- input projection ----
  gemm_kernel<128, 128><<<gblocks, 256, 0, stream>>>(xb, wIn, bIn, hb, hf);

  // ---- GIN layers ----
  for (int i = 0; i < 5; ++i) {
    agg_kernel<<<(N + 3) / 4, 256, 0, stream>>>(hb, rowptr, colx, eps_g, i, zb, N);
    if (i == 0)
      mlp_fused_kernel<1><<<mblocks, 1024, 0, stream>>>(
          zb, w1f + (size_t)i * 384 * 128, b1f + (size_t)i * 384,
          w2f + (size_t)i * 256 * 384, b2f + (size_t)i * 256,
          w3f + (size_t)i * 128 * 256, b3f + (size_t)i * 128, hb, hf);
    else
      mlp_fused_kernel<2><<<mblocks, 1024, 0, stream>>>(
          zb, w1f + (size_t)i * 384 * 128, b1f + (size_t)i * 384,
          w2f + (size_t)i * 256 * 384, b2f + (size_t)i * 256,
          w3f + (size_t)i * 128 * 256, b3f + (size_t)i * 128, hb, hf);
  }

  // ---- readout + classifier ----
  readout_kernel<<<G, 1024, 0, stream>>>(hf, gptr, gbuf);
  classifier_kernel<<<G, 128, 0, stream>>>(gbuf, cw1f, cb1f, cw2f, cb2f, cw3f, cb3f,
                                           (float*)d_out);
}

// Round 17
// 825.805 us; speedup vs baseline: 1.0680x; 1.0680x over previous
//
#include <hip/hip_runtime.h>
#include <hip/hip_bf16.h>

#define GLOBAL_AS __attribute__((address_space(1)))
#define LDS_AS    __attribute__((address_space(3)))

typedef __attribute__((ext_vector_type(4))) float  f32x4;
typedef __attribute__((ext_vector_type(8))) short  bf16x8;

static constexpr int   H      = 128;
static constexpr float BN_EPS = 1e-5f;

__device__ __forceinline__ float bf2f(ushort u) {
  union { unsigned u; float f; } x; x.u = ((unsigned)u) << 16; return x.f;
}
__device__ __forceinline__ ushort f2bf(float f) {
  union { float f; unsigned u; } x; x.f = f;
  unsigned r = x.u + 0x7fffu + ((x.u >> 16) & 1u);
  return (ushort)(r >> 16);
}

// ---------------- unified weight folding (single launch) ----------------
__device__ __forceinline__ void fold_pack_one(const float* __restrict__ W,
                                              const float* __restrict__ b,
                                              const float* __restrict__ bn,
                                              int K, int NOUT, int idx,
                                              ushort* __restrict__ Wp,
                                              float* __restrict__ bout) {
  int o = idx / K, k = idx - o * K;
  float scale = 1.0f, shift = 0.0f;
  if (bn != nullptr) {
    float g = bn[o], be = bn[NOUT + o], m = bn[2 * NOUT + o], v = bn[3 * NOUT + o];
    scale = g * rsqrtf(v + BN_EPS);
    shift = be - m * scale;
  }
  int gt = o >> 4, lr = o & 15, ks = k >> 5, lk = (k >> 3) & 3, e = k & 7;
  size_t pos = ((((size_t)gt * (K / 32) + ks) * 64) + lk * 16 + lr) * 8 + e;
  Wp[pos] = f2bf(W[(size_t)k * NOUT + o] * scale);
  if (k == 0) bout[o] = b[o] * scale + shift;
}

__device__ __forceinline__ void fold_f32_one(const float* __restrict__ W,
                                             const float* __restrict__ b,
                                             const float* __restrict__ bn,
                                             int K, int NOUT, int idx,
                                             float* __restrict__ Wt,
                                             float* __restrict__ bout) {
  int o = idx / K, k = idx - o * K;
  float scale = 1.0f, shift = 0.0f;
  if (bn != nullptr) {
    float g = bn[o], be = bn[NOUT + o], m = bn[2 * NOUT + o], v = bn[3 * NOUT + o];
    scale = g * rsqrtf(v + BN_EPS);
    shift = be - m * scale;
  }
  Wt[(size_t)o * K + k] = W[(size_t)k * NOUT + o] * scale;
  if (k == 0) bout[o] = b[o] * scale + shift;
}

__global__ __launch_bounds__(256) void fold_all_kernel(
    const float* __restrict__ in_W, const float* __restrict__ in_b, const float* __restrict__ in_bn,
    const float* __restrict__ W1, const float* __restrict__ b1, const float* __restrict__ bn1,
    const float* __restrict__ W2, const float* __restrict__ b2, const float* __restrict__ bn2,
    const float* __restrict__ W3, const float* __restrict__ b3, const float* __restrict__ nbn,
    const float* __restrict__ cW1, const float* __restrict__ cb1, const float* __restrict__ cbn1,
    const float* __restrict__ cW2, const float* __restrict__ cb2, const float* __restrict__ cbn2,
    const float* __restrict__ fW, const float* __restrict__ fb,
    ushort* __restrict__ wIn, float* __restrict__ bIn,
    ushort* __restrict__ w1f, float* __restrict__ b1f,
    ushort* __restrict__ w2f, float* __restrict__ b2f,
    ushort* __restrict__ w3f, float* __restrict__ b3f,
    float* __restrict__ cw1f, float* __restrict__ cb1f,
    float* __restrict__ cw2f, float* __restrict__ cb2f,
    float* __restrict__ cw3f, float* __restrict__ cb3f) {
  int idx = blockIdx.x * 256 + threadIdx.x;
  if (idx < 16384) {
    fold_pack_one(in_W, in_b, in_bn, 128, 128, idx, wIn, bIn);
    return;
  }
  idx -= 16384;
  if (idx < 5 * 180224) {
    int layer = idx / 180224;
    int r = idx - layer * 180224;
    if (r < 49152) {
      fold_pack_one(W1 + (size_t)layer * 49152, b1 + (size_t)layer * 384,
                    bn1 + (size_t)layer * 4 * 384, 128, 384, r,
                    w1f + (size_t)layer * 49152, b1f + (size_t)layer * 384);
    } else if (r < 147456) {
      fold_pack_one(W2 + (size_t)layer * 98304, b2 + (size_t)layer * 256,
                    bn2 + (size_t)layer * 4 * 256, 384, 256, r - 49152,
                    w2f + (size_t)layer * 98304, b2f + (size_t)layer * 256);
    } else {
      fold_pack_one(W3 + (size_t)layer * 32768, b3 + (size_t)layer * 128,
                    nbn + (size_t)layer * 4 * 128, 256, 128, r - 147456,
                    w3f + (size_t)layer * 32768, b3f + (size_t)layer * 128);
    }
    return;
  }
  idx -= 5 * 180224;
  if (idx < 49152) { fold_f32_one(cW1, cb1, cbn1, 384, 128, idx, cw1f, cb1f); return; }
  idx -= 49152;
  if (idx < 8192)  { fold_f32_one(cW2, cb2, cbn2, 128, 64, idx, cw2f, cb2f); return; }
  idx -= 8192;
  if (idx < 384)   { fold_f32_one(fW, fb, nullptr, 64, 6, idx, cw3f, cb3f); return; }
}

// ---------------- fp32 -> bf16 convert (x) ----------------
__global__ void cvt4_kernel(const float* __restrict__ x, ushort* __restrict__ xb, int n4) {
  int i = blockIdx.x * blockDim.x + threadIdx.x;
  if (i >= n4) return;
  float4 v = ((const float4*)x)[i];
  ushort4 o; o.x = f2bf(v.x); o.y = f2bf(v.y); o.z = f2bf(v.z); o.w = f2bf(v.w);
  ((ushort4*)xb)[i] = o;
}

// ---------------- CSR build ----------------
__global__ void hist_kernel(const int* __restrict__ idx, int n, int* __restrict__ cnt) {
  int i = blockIdx.x * blockDim.x + threadIdx.x;
  if (i < n) atomicAdd(&cnt[idx[i]], 1);
}

__global__ void gbound_kernel(const int* __restrict__ batch, int N, int G,
                              int* __restrict__ gptr) {
  int i = blockIdx.x * blockDim.x + threadIdx.x;
  if (i >= N) return;
  int b = batch[i];
  int prev = (i == 0) ? -1 : batch[i - 1];
  for (int g = prev + 1; g <= b; ++g) gptr[g] = i;
  if (i == N - 1) for (int g = b + 1; g <= G; ++g) gptr[g] = N;
}

__global__ void block_sum_kernel(const int* __restrict__ v, int n, int* __restrict__ bsum) {
  __shared__ int s[256];
  int i = blockIdx.x * 256 + threadIdx.x;
  int x = (i < n) ? v[i] : 0;
  s[threadIdx.x] = x; __syncthreads();
  for (int off = 128; off > 0; off >>= 1) {
    if (threadIdx.x < (unsigned)off) s[threadIdx.x] += s[threadIdx.x + off];
    __syncthreads();
  }
  if (threadIdx.x == 0) bsum[blockIdx.x] = s[0];
}

__global__ void scan_block_kernel(int* __restrict__ bsum, int nb,
                                  int* __restrict__ last_out, int total) {
  __shared__ int s[256];
  __shared__ int carry;
  if (threadIdx.x == 0) carry = 0;
  __syncthreads();
  for (int base = 0; base < nb; base += 256) {
    int i = base + threadIdx.x;
    int x = (i < nb) ? bsum[i] : 0;
    s[threadIdx.x] = x; __syncthreads();
    for (int off = 1; off < 256; off <<= 1) {
      int add = (threadIdx.x >= (unsigned)off) ? s[threadIdx.x - off] : 0;
      __syncthreads();
      s[threadIdx.x] += add;
      __syncthreads();
    }
    if (i < nb) bsum[i] = carry + s[threadIdx.x] - x;   // exclusive
    __syncthreads();
    if (threadIdx.x == 0) carry += s[255];
    __syncthreads();
  }
  if (last_out && threadIdx.x == 0) *last_out = total;
}

__global__ void scan_final_kernel(const int* __restrict__ v, int n, const int* __restrict__ bsum,
                                  int* __restrict__ rowptr, int* __restrict__ cursor) {
  __shared__ int s[256];
  int i = blockIdx.x * 256 + threadIdx.x;
  int x = (i < n) ? v[i] : 0;
  s[threadIdx.x] = x; __syncthreads();
  for (int off = 1; off < 256; off <<= 1) {
    int add = (threadIdx.x >= (unsigned)off) ? s[threadIdx.x - off] : 0;
    __syncthreads();
    s[threadIdx.x] += add;
    __syncthreads();
  }
  if (i < n) {
    int excl = bsum[blockIdx.x] + s[threadIdx.x] - x;
    rowptr[i] = excl;
    if (cursor) cursor[i] = excl;
  }
}

// dst-range-partitioned scatter with nontemporal edge loads (round-16, kept to isolate)
__global__ __launch_bounds__(256) void scatter_part_kernel(
    const int* __restrict__ src, const int* __restrict__ dst, int E,
    int* __restrict__ cursor, int* __restrict__ col, int npp) {
  const int part  = blockIdx.x & 7;
  const int chunk = blockIdx.x >> 3;
  const int lo = part * npp, hi = lo + npp;
  const int i0 = chunk * 1024 + threadIdx.x * 4;
  if (i0 + 3 < E) {
    int d0 = __builtin_nontemporal_load(dst + i0 + 0);
    int d1 = __builtin_nontemporal_load(dst + i0 + 1);
    int d2 = __builtin_nontemporal_load(dst + i0 + 2);
    int d3 = __builtin_nontemporal_load(dst + i0 + 3);
    if (d0 >= lo && d0 < hi) { int p = atomicAdd(&cursor[d0], 1); col[p] = __builtin_nontemporal_load(src + i0 + 0); }
    if (d1 >= lo && d1 < hi) { int p = atomicAdd(&cursor[d1], 1); col[p] = __builtin_nontemporal_load(src + i0 + 1); }
    if (d2 >= lo && d2 < hi) { int p = atomicAdd(&cursor[d2], 1); col[p] = __builtin_nontemporal_load(src + i0 + 2); }
    if (d3 >= lo && d3 < hi) { int p = atomicAdd(&cursor[d3], 1); col[p] = __builtin_nontemporal_load(src + i0 + 3); }
  } else {
    for (int u = 0; u < 4; ++u) {
      int i = i0 + u;
      if (i < E) {
        int d = dst[i];
        if (d >= lo && d < hi) { int p = atomicAdd(&cursor[d], 1); col[p] = src[i]; }
      }
    }
  }
}

// ---------------- GIN aggregation (round-12 proven: 4-deep gather unroll) --------------
__global__ __launch_bounds__(256) void agg_kernel(
    const ushort* __restrict__ hb,
    const int* __restrict__ rowptr, const int* __restrict__ col,
    const float* __restrict__ eps_g, int layer,
    ushort* __restrict__ z, int n) {
  int node = blockIdx.x * 4 + (threadIdx.x >> 6);
  if (node >= n) return;
  const int lane = threadIdx.x & 63;
  const int l16  = lane & 15;
  const int grp  = lane >> 4;
  const int s = rowptr[node], e = rowptr[node + 1];
  float a0 = 0.f, a1 = 0.f, a2 = 0.f, a3 = 0.f, a4 = 0.f, a5 = 0.f, a6 = 0.f, a7 = 0.f;
  const size_t co = (size_t)l16 * 8;
  int j = s + grp;
  for (; j + 12 < e; j += 16) {
    int i0 = col[j], i1 = col[j + 4], i2 = col[j + 8], i3 = col[j + 12];
    bf16x8 v0 = *(const bf16x8*)(hb + (size_t)i0 * H + co);
    bf16x8 v1 = *(const bf16x8*)(hb + (size_t)i1 * H + co);
    bf16x8 v2 = *(const bf16x8*)(hb + (size_t)i2 * H + co);
    bf16x8 v3 = *(const bf16x8*)(hb + (size_t)i3 * H + co);
    a0 += (bf2f((ushort)v0[0]) + bf2f((ushort)v1[0])) + (bf2f((ushort)v2[0]) + bf2f((ushort)v3[0]));
    a1 += (bf2f((ushort)v0[1]) + bf2f((ushort)v1[1])) + (bf2f((ushort)v2[1]) + bf2f((ushort)v3[1]));
    a2 += (bf2f((ushort)v0[2]) + bf2f((ushort)v1[2])) + (bf2f((ushort)v2[2]) + bf2f((ushort)v3[2]));
    a3 += (bf2f((ushort)v0[3]) + bf2f((ushort)v1[3])) + (bf2f((ushort)v2[3]) + bf2f((ushort)v3[3]));
    a4 += (bf2f((ushort)v0[4]) + bf2f((ushort)v1[4])) + (bf2f((ushort)v2[4]) + bf2f((ushort)v3[4]));
    a5 += (bf2f((ushort)v0[5]) + bf2f((ushort)v1[5])) + (bf2f((ushort)v2[5]) + bf2f((ushort)v3[5]));
    a6 += (bf2f((ushort)v0[6]) + bf2f((ushort)v1[6])) + (bf2f((ushort)v2[6]) + bf2f((ushort)v3[6]));
    a7 += (bf2f((ushort)v0[7]) + bf2f((ushort)v1[7])) + (bf2f((ushort)v2[7]) + bf2f((ushort)v3[7]));
  }
  for (; j + 4 < e; j += 8) {
    int i0 = col[j], i1 = col[j + 4];
    bf16x8 v0 = *(const bf16x8*)(hb + (size_t)i0 * H + co);
    bf16x8 v1 = *(const bf16x8*)(hb + (size_t)i1 * H + co);
    a0 += bf2f((ushort)v0[0]) + bf2f((ushort)v1[0]);
    a1 += bf2f((ushort)v0[1]) + bf2f((ushort)v1[1]);
    a2 += bf2f((ushort)v0[2]) + bf2f((ushort)v1[2]);
    a3 += bf2f((ushort)v0[3]) + bf2f((ushort)v1[3]);
    a4 += bf2f((ushort)v0[4]) + bf2f((ushort)v1[4]);
    a5 += bf2f((ushort)v0[5]) + bf2f((ushort)v1[5]);
    a6 += bf2f((ushort)v0[6]) + bf2f((ushort)v1[6]);
    a7 += bf2f((ushort)v0[7]) + bf2f((ushort)v1[7]);
  }
  if (j < e) {
    bf16x8 v0 = *(const bf16x8*)(hb + (size_t)col[j] * H + co);
    a0 += bf2f((ushort)v0[0]); a1 += bf2f((ushort)v0[1]);
    a2 += bf2f((ushort)v0[2]); a3 += bf2f((ushort)v0[3]);
    a4 += bf2f((ushort)v0[4]); a5 += bf2f((ushort)v0[5]);
    a6 += bf2f((ushort)v0[6]); a7 += bf2f((ushort)v0[7]);
  }
  a0 += __shfl_xor(a0, 16); a0 += __shfl_xor(a0, 32);
  a1 += __shfl_xor(a1, 16); a1 += __shfl_xor(a1, 32);
  a2 += __shfl_xor(a2, 16); a2 += __shfl_xor(a2, 32);
  a3 += __shfl_xor(a3, 16); a3 += __shfl_xor(a3, 32);
  a4 += __shfl_xor(a4, 16); a4 += __shfl_xor(a4, 32);
  a5 += __shfl_xor(a5, 16); a5 += __shfl_xor(a5, 32);
  a6 += __shfl_xor(a6, 16); a6 += __shfl_xor(a6, 32);
  a7 += __shfl_xor(a7, 16); a7 += __shfl_xor(a7, 32);
  float sx, sy;
  if      (grp == 0) { sx = a0; sy = a1; }
  else if (grp == 1) { sx = a2; sy = a3; }
  else if (grp == 2) { sx = a4; sy = a5; }
  else               { sx = a6; sy = a7; }
  const int c0 = l16 * 8 + grp * 2;
  float ep = 1.0f + eps_g[layer];
  ushort2 hs = *(const ushort2*)(hb + (size_t)node * H + c0);
  ushort2 o;
  o.x = f2bf(ep * bf2f(hs.x) + sx);
  o.y = f2bf(ep * bf2f(hs.y) + sy);
  *(ushort2*)(z + (size_t)node * H + c0) = o;
}

// ---------------- input projection GEMM (M=64, packed weights) ----------------
template<int K, int NOUT>
__global__ __launch_bounds__(256) void gemm_kernel(
    const ushort* __restrict__ A, const ushort* __restrict__ Wp,
    const float* __restrict__ bias,
    ushort* __restrict__ outb, float* __restrict__ hf) {
  constexpr int ROWB = 2 * K;
  __shared__ __align__(16) char lds[64 * ROWB];
  const int t = threadIdx.x;
  const long row0 = (long)blockIdx.x * 64;
  const char* Ab = (const char*)(A + (size_t)row0 * K);

  constexpr int ITERS = (64 * ROWB) / (256 * 16);
#pragma unroll
  for (int it = 0; it < ITERS; ++it) {
    int ob = (it * 256 + t) * 16;
    int r = ob / ROWB;
    int c = ob - r * ROWB;
    int sb = r * ROWB + (c ^ ((r & 7) << 4));
    __builtin_amdgcn_global_load_lds((const GLOBAL_AS void*)(Ab + sb),
                                     (LDS_AS void*)(lds + ob), 16, 0, 0);
  }
  __syncthreads();

  const int l  = t & 63;
  const int w  = t >> 6;
  const int lr = l & 15;
  const int lk = l >> 4;
  constexpr int CPW = NOUT / 4;
  constexpr int NCT = CPW / 16;

  for (int ct = 0; ct < NCT; ++ct) {
    const int colbase = w * CPW + ct * 16;
    const ushort* tb = Wp + ((size_t)(colbase >> 4) * (K / 32)) * 512;
    f32x4 acc[4] = {};
#pragma unroll
    for (int ks = 0; ks < K / 32; ++ks) {
      bf16x8 bfr = *(const bf16x8*)(tb + ks * 512 + l * 8);
#pragma unroll
      for (int rt = 0; rt < 4; ++rt) {
        const int rr = rt * 16 + lr;
        const int kb = ks * 64 + lk * 16;
        bf16x8 afr = *(const bf16x8*)(lds + rr * ROWB + (kb ^ ((rr & 7) << 4)));
        acc[rt] = __builtin_amdgcn_mfma_f32_16x16x32_bf16(bfr, afr, acc[rt], 0, 0, 0);
      }
    }
    const int c0 = colbase + lk * 4;
    const float b0 = bias[c0], b1 = bias[c0 + 1], b2 = bias[c0 + 2], b3 = bias[c0 + 3];
#pragma unroll
    for (int rt = 0; rt < 4; ++rt) {
      const long grow = row0 + rt * 16 + lr;
      float v0 = fmaxf(acc[rt][0] + b0, 0.f);
      float v1 = fmaxf(acc[rt][1] + b1, 0.f);
      float v2 = fmaxf(acc[rt][2] + b2, 0.f);
      float v3 = fmaxf(acc[rt][3] + b3, 0.f);
      *(float4*)(hf + grow * H + c0) = make_float4(v0, v1, v2, v3);
      ushort4 sv; sv.x = f2bf(v0); sv.y = f2bf(v1); sv.z = f2bf(v2); sv.w = f2bf(v3);
      *(ushort4*)(outb + grow * NOUT + c0) = sv;
    }
  }
}

// ---------------- fused per-layer MLP (round-14 proven; M=64, 512 thr, 64KB LDS) ------
// Design-space map: M=32/256thr=76us, M=64/256thr=83us, M=64/512thr=66us (BEST),
// M=128/1024thr=78us (1 block/CU -> barrier lockstep, round-16). Keep M=64/512.
template<int HMODE>  // 1: write h (no residual), 2: h += old
__global__ __launch_bounds__(512, 4) void mlp_fused_kernel(
    const ushort* __restrict__ zin,
    const ushort* __restrict__ w1, const float* __restrict__ bb1,
    const ushort* __restrict__ w2, const float* __restrict__ bb2,
    const ushort* __restrict__ w3, const float* __restrict__ bb3,
    ushort* __restrict__ hb, float* __restrict__ hf) {
  __shared__ __align__(16) char lds[64 * 1024];
  char* t1 = lds;               // [64][768B]
  char* zz = lds + 48 * 1024;   // [64][256B]
  char* t2 = lds + 32 * 1024;   // [64][512B], overlays t1-top + zz after stage-2 reads

  const int t = threadIdx.x;
  const long row0 = (long)blockIdx.x * 64;
  const char* Ab = (const char*)(zin + (size_t)row0 * 128);

#pragma unroll
  for (int it = 0; it < 2; ++it) {
    int ob = (it * 512 + t) * 16;
    int r = ob >> 8;
    int c = ob & 255;
    int sb = r * 256 + (c ^ ((r & 7) << 4));
    __builtin_amdgcn_global_load_lds((const GLOBAL_AS void*)(Ab + sb),
                                     (LDS_AS void*)(zz + ob), 16, 0, 0);
  }
  __syncthreads();

  const int l  = t & 63;
  const int w  = t >> 6;    // 0..7
  const int lr = l & 15;
  const int lk = l >> 4;

  // ---- stage 1: wave cols [w*48,+48) = 3 tiles, rows 0..63
  {
    f32x4 acc[3][4] = {};
#pragma unroll
    for (int ks = 0; ks < 4; ++ks) {
      bf16x8 afr[4];
#pragma unroll
      for (int rt = 0; rt < 4; ++rt) {
        const int rr = rt * 16 + lr;
        afr[rt] = *(const bf16x8*)(zz + rr * 256 + ((ks * 64 + lk * 16) ^ ((rr & 7) << 4)));
      }
#pragma unroll
      for (int ct = 0; ct < 3; ++ct) {
        bf16x8 bfr = *(const bf16x8*)(w1 + ((size_t)(w * 3 + ct) * 4 + ks) * 512 + l * 8);
#pragma unroll
        for (int rt = 0; rt < 4; ++rt)
          acc[ct][rt] = __builtin_amdgcn_mfma_f32_16x16x32_bf16(bfr, afr[rt], acc[ct][rt], 0, 0, 0);
      }
    }
#pragma unroll
    for (int ct = 0; ct < 3; ++ct) {
      const int c0 = w * 48 + ct * 16 + lk * 4;
      const float b0 = bb1[c0], b1 = bb1[c0 + 1], b2 = bb1[c0 + 2], b3 = bb1[c0 + 3];
#pragma unroll
      for (int rt = 0; rt < 4; ++rt) {
        const int rr = rt * 16 + lr;
        ushort4 sv;
        sv.x = f2bf(fmaxf(acc[ct][rt][0] + b0, 0.f));
        sv.y = f2bf(fmaxf(acc[ct][rt][1] + b1, 0.f));
        sv.z = f2bf(fmaxf(acc[ct][rt][2] + b2, 0.f));
        sv.w = f2bf(fmaxf(acc[ct][rt][3] + b3, 0.f));
        *(ushort4*)(t1 + rr * 768 + ((c0 * 2) ^ ((rr & 7) << 4))) = sv;
      }
    }
  }
  __syncthreads();

  // ---- stage 2: wave cols [w*32,+32) = 2 tiles, K=384
  {
    f32x4 acc[2][4] = {};
#pragma unroll
    for (int ks = 0; ks < 12; ++ks) {
      bf16x8 afr[4];
#pragma unroll
      for (int rt = 0; rt < 4; ++rt) {
        const int rr = rt * 16 + lr;
        afr[rt] = *(const bf16x8*)(t1 + rr * 768 + ((ks * 64 + lk * 16) ^ ((rr & 7) << 4)));
      }
#pragma unroll
      for (int ct = 0; ct < 2; ++ct) {
        bf16x8 bfr = *(const bf16x8*)(w2 + ((size_t)(w * 2 + ct) * 12 + ks) * 512 + l * 8);
#pragma unroll
        for (int rt = 0; rt < 4; ++rt)
          acc[ct][rt] = __builtin_amdgcn_mfma_f32_16x16x32_bf16(bfr, afr[rt], acc[ct][rt], 0, 0, 0);
      }
    }
    __syncthreads();   // ALL t1/zz reads done; t2 may overlay [32K,64K)
#pragma unroll
    for (int ct = 0; ct < 2; ++ct) {
      const int c0 = w * 32 + ct * 16 + lk * 4;
      const float b0 = bb2[c0], b1 = bb2[c0 + 1], b2 = bb2[c0 + 2], b3 = bb2[c0 + 3];
#pragma unroll
      for (int rt = 0; rt < 4; ++rt) {
        const int rr = rt * 16 + lr;
        ushort4 sv;
        sv.x = f2bf(fmaxf(acc[ct][rt][0] + b0, 0.f));
        sv.y = f2bf(fmaxf(acc[ct][rt][1] + b1, 0.f));
        sv.z = f2bf(fmaxf(acc[ct][rt][2] + b2, 0.f));
        sv.w = f2bf(fmaxf(acc[ct][rt][3] + b3, 0.f));
        *(ushort4*)(t2 + rr * 512 + ((c0 * 2) ^ ((rr & 7) << 4))) = sv;
      }
    }
  }
  __syncthreads();

  // ---- stage 3: wave cols [w*16,+16) = 1 tile
  {
    f32x4 acc[4] = {};
#pragma unroll
    for (int ks = 0; ks < 8; ++ks) {
      bf16x8 afr[4];
#pragma unroll
      for (int rt = 0; rt < 4; ++rt) {
        const int rr = rt * 16 + lr;
        afr[rt] = *(const bf16x8*)(t2 + rr * 512 + ((ks * 64 + lk * 16) ^ ((rr & 7) << 4)));
      }
      bf16x8 bfr = *(const bf16x8*)(w3 + ((size_t)w * 8 + ks) * 512 + l * 8);
#pragma unroll
      for (int rt = 0; rt < 4; ++rt)
        acc[rt] = __builtin_amdgcn_mfma_f32_16x16x32_bf16(bfr, afr[rt], acc[rt], 0, 0, 0);
    }
    const int c0 = w * 16 + lk * 4;
    const float b0 = bb3[c0], b1 = bb3[c0 + 1], b2 = bb3[c0 + 2], b3v = bb3[c0 + 3];
#pragma unroll
    for (int rt = 0; rt < 4; ++rt) {
      const long grow = row0 + rt * 16 + lr;
      float v0 = fmaxf(acc[rt][0] + b0, 0.f);
      float v1 = fmaxf(acc[rt][1] + b1, 0.f);
      float v2 = fmaxf(acc[rt][2] + b2, 0.f);
      float v3 = fmaxf(acc[rt][3] + b3v, 0.f);
      float4* hp = (float4*)(hf + grow * H + c0);
      if (HMODE == 2) {
        float4 o = *hp;
        v0 += o.x; v1 += o.y; v2 += o.z; v3 += o.w;
      }
      *hp = make_float4(v0, v1, v2, v3);
      ushort4 sv; sv.x = f2bf(v0); sv.y = f2bf(v1); sv.z = f2bf(v2); sv.w = f2bf(v3);
      *(ushort4*)(hb + grow * H + c0) = sv;
    }
  }
}

// ---------------- readout: sum / mean / max per graph (round-15 proven) ----------------
__global__ __launch_bounds__(1024) void readout_kernel(const float* __restrict__ hf,
                                                       const int* __restrict__ gptr,
                                                       float* __restrict__ g) {
  __shared__ float ssum[8][128];
  __shared__ float smax[8][128];
  const int gi  = blockIdx.x;
  const int t   = threadIdx.x;
  const int grp = t >> 7;      // 0..7
  const int c   = t & 127;
  const int s = gptr[gi], e = gptr[gi + 1];
  float sum = 0.f, mx = -INFINITY;
  for (int n = s + grp; n < e; n += 8) {
    float v = hf[(size_t)n * H + c];
    sum += v; mx = fmaxf(mx, v);
  }
  ssum[grp][c] = sum;
  smax[grp][c] = mx;
  __syncthreads();
  if (t < 128) {
    float s0 = 0.f, m0 = -INFINITY;
#pragma unroll
    for (int k = 0; k < 8; ++k) { s0 += ssum[k][t]; m0 = fmaxf(m0, smax[k][t]); }
    const int cnt = e - s;
    g[gi * 384 + t]       = s0;
    g[gi * 384 + 128 + t] = s0 / fmaxf((float)cnt, 1.f);
    g[gi * 384 + 256 + t] = (cnt > 0) ? m0 : 0.f;
  }
}

// ---------------- classifier head ----------------
__global__ __launch_bounds__(128) void classifier_kernel(
    const float* __restrict__ g,
    const float* __restrict__ W1, const float* __restrict__ b1,
    const float* __restrict__ W2, const float* __restrict__ b2,
    const float* __restrict__ W3, const float* __restrict__ b3,
    float* __restrict__ out) {
  __shared__ float row[384];
  __shared__ float f1[128];
  __shared__ float f2s[64];
  int gi = blockIdx.x, t = threadIdx.x;
  for (int i = t; i < 384; i += 128) row[i] = g[gi * 384 + i];
  __syncthreads();
  float a = b1[t];
  for (int k = 0; k < 384; ++k) a += row[k] * W1[t * 384 + k];
  f1[t] = fmaxf(a, 0.f);
  __syncthreads();
  if (t < 64) {
    float a2 = b2[t];
    for (int k = 0; k < 128; ++k) a2 += f1[k] * W2[t * 128 + k];
    f2s[t] = fmaxf(a2, 0.f);
  }
  __syncthreads();
  if (t < 6) {
    float a3 = b3[t];
    for (int k = 0; k < 64; ++k) a3 += f2s[k] * W3[t * 64 + k];
    out[gi * 6 + t] = a3;
  }
}

// ---------------- launcher ----------------
extern "C" void kernel_launch(void* const* d_in, const int* in_sizes, int n_in,
                              void* d_out, int out_size, void* d_ws, size_t ws_size,
                              hipStream_t stream) {
  (void)n_in; (void)ws_size;
  const float* x     = (const float*)d_in[0];
  const int*   eidx  = (const int*)d_in[1];
  const int*   batch = (const int*)d_in[2];
  const float* in_W  = (const float*)d_in[3];
  const float* in_b  = (const float*)d_in[4];
  const float* in_bn = (const float*)d_in[5];
  const float* W1    = (const float*)d_in[6];
  const float* b1    = (const float*)d_in[7];
  const float* bn1   = (const float*)d_in[8];
  const float* W2    = (const float*)d_in[9];
  const float* b2    = (const float*)d_in[10];
  const float* bn2   = (const float*)d_in[11];
  const float* W3    = (const float*)d_in[12];
  const float* b3    = (const float*)d_in[13];
  const float* eps_g = (const float*)d_in[14];
  const float* nbn   = (const float*)d_in[15];
  const float* cW1   = (const float*)d_in[16];
  const float* cb1   = (const float*)d_in[17];
  const float* cbn1  = (const float*)d_in[18];
  const float* cW2   = (const float*)d_in[19];
  const float* cb2   = (const float*)d_in[20];
  const float* cbn2  = (const float*)d_in[21];
  const float* fW    = (const float*)d_in[22];
  const float* fb    = (const float*)d_in[23];

  const int N  = in_sizes[0] / 128;
  const int E  = in_sizes[1] / 2;
  const int G  = out_size / 6;
  const int Mp = ((N + 63) / 64) * 64;
  const int gblocks = Mp / 64;            // input projection + fused MLP (M=64)
  const int npp = (N + 7) / 8;            // nodes per scatter partition
  const int nchunks = (E + 1023) / 1024;  // edge chunks of 1024

  char* p = (char*)d_ws;
  auto alloc = [&](size_t bytes) -> char* {
    char* r = p; p += (bytes + 255) & ~(size_t)255; return r;
  };
  ushort* hb     = (ushort*)alloc((size_t)Mp * H * 2);
  ushort* zb     = (ushort*)alloc((size_t)Mp * H * 2);
  ushort* xb     = (ushort*)alloc((size_t)Mp * H * 2);
  float*  hf     = (float*)alloc((size_t)Mp * H * 4);
  int*    deg    = (int*)alloc((size_t)N * 4);
  int*    rowptr = (int*)alloc((size_t)(N + 1) * 4);
  int*    cursor = (int*)alloc((size_t)N * 4);
  int*    colx   = (int*)alloc((size_t)E * 4);
  int*    bsum   = (int*)alloc(4096);
  int*    gptr   = (int*)alloc((size_t)(G + 1) * 4);
  float*  gbuf   = (float*)alloc((size_t)G * 384 * 4);
  ushort* wIn    = (ushort*)alloc(128 * 128 * 2);
  float*  bIn    = (float*)alloc(128 * 4);
  ushort* w1f    = (ushort*)alloc((size_t)5 * 384 * 128 * 2);
  float*  b1f    = (float*)alloc((size_t)5 * 384 * 4);
  ushort* w2f    = (ushort*)alloc((size_t)5 * 256 * 384 * 2);
  float*  b2f    = (float*)alloc((size_t)5 * 256 * 4);
  ushort* w3f    = (ushort*)alloc((size_t)5 * 128 * 256 * 2);
  float*  b3f    = (float*)alloc((size_t)5 * 128 * 4);
  float*  cw1f   = (float*)alloc(128 * 384 * 4);
  float*  cb1f   = (float*)alloc(128 * 4);
  float*  cw2f   = (float*)alloc(64 * 128 * 4);
  float*  cb2f   = (float*)alloc(64 * 4);
  float*  cw3f   = (float*)alloc(6 * 64 * 4);
  float*  cb3f   = (float*)alloc(6 * 4);

  // ---- weight folding: ONE launch for all 22 matrices ----
  const int fold_total = 16384 + 5 * 180224 + 49152 + 8192 + 384;
  fold_all_kernel<<<(fold_total + 255) / 256, 256, 0, stream>>>(
      in_W, in_b, in_bn, W1, b1, bn1, W2, b2, bn2, W3, b3, nbn,
      cW1, cb1, cbn1, cW2, cb2, cbn2, fW, fb,
      wIn, bIn, w1f, b1f, w2f, b2f, w3f, b3f,
      cw1f, cb1f, cw2f, cb2f, cw3f, cb3f);

  // ---- x -> bf16 ----
  cvt4_kernel<<<(N * 128 / 4 + 255) / 256, 256, 0, stream>>>(x, xb, N * 128 / 4);

  // ---- CSR build (partitioned scatter) + graph ranges (sorted-batch boundaries) ----
  hipMemsetAsync(deg, 0, (size_t)N * 4, stream);
  hist_kernel<<<(E + 255) / 256, 256, 0, stream>>>(eidx + E, E, deg);
  gbound_kernel<<<(N + 255) / 256, 256, 0, stream>>>(batch, N, G, gptr);
  const int nb = (N + 255) / 256;
  block_sum_kernel<<<nb, 256, 0, stream>>>(deg, N, bsum);
  scan_block_kernel<<<1, 256, 0, stream>>>(bsum, nb, rowptr + N, E);
  scan_final_kernel<<<nb, 256, 0, stream>>>(deg, N, bsum, rowptr, cursor);
  scatter_part_kernel<<<nchunks * 8, 256, 0, stream>>>(eidx, eidx + E, E, cursor, colx, npp);

  // ---- input projection ----
  gemm_kernel<128, 128><<<gblocks, 256, 0, stream>>>(xb, wIn, bIn, hb, hf);

  // ---- GIN layers ----
  for (int i = 0; i < 5; ++i) {
    agg_kernel<<<(N + 3) / 4, 256, 0, stream>>>(hb, rowptr, colx, eps_g, i, zb, N);
    if (i == 0)
      mlp_fused_kernel<1><<<gblocks, 512, 0, stream>>>(
          zb, w1f + (size_t)i * 384 * 128, b1f + (size_t)i * 384,
          w2f + (size_t)i * 256 * 384, b2f + (size_t)i * 256,
          w3f + (size_t)i * 128 * 256, b3f + (size_t)i * 128, hb, hf);
    else
      mlp_fused_kernel<2><<<gblocks, 512, 0, stream>>>(
          zb, w1f + (size_t)i * 384 * 128, b1f + (size_t)i * 384,
          w2f + (size_t)i * 256 * 384, b2f + (size_t)i * 256,
          w3f + (size_t)i * 128 * 256, b3f + (size_t)i * 128, hb, hf);
  }

  // ---- readout + classifier ----
  readout_kernel<<<G, 1024, 0, stream>>>(hf, gptr, gbuf);
  classifier_kernel<<<G, 128, 0, stream>>>(gbuf, cw1f, cb1f, cw2f, cb2f, cw3f, cb3f,
                                           (float*)d_out);
}

// Round 18
// 820.602 us; speedup vs baseline: 1.0747x; 1.0063x over previous
//
#include <hip/hip_runtime.h>
#include <hip/hip_bf16.h>

#define GLOBAL_AS __attribute__((address_space(1)))
#define LDS_AS    __attribute__((address_space(3)))

typedef __attribute__((ext_vector_type(4))) float  f32x4;
typedef __attribute__((ext_vector_type(8))) short  bf16x8;

static constexpr int   H      = 128;
static constexpr float BN_EPS = 1e-5f;

__device__ __forceinline__ float bf2f(ushort u) {
  union { unsigned u; float f; } x; x.u = ((unsigned)u) << 16; return x.f;
}
__device__ __forceinline__ ushort f2bf(float f) {
  union { float f; unsigned u; } x; x.f = f;
  unsigned r = x.u + 0x7fffu + ((x.u >> 16) & 1u);
  return (ushort)(r >> 16);
}

// ---------------- unified weight folding (single launch) ----------------
__device__ __forceinline__ void fold_pack_one(const float* __restrict__ W,
                                              const float* __restrict__ b,
                                              const float* __restrict__ bn,
                                              int K, int NOUT, int idx,
                                              ushort* __restrict__ Wp,
                                              float* __restrict__ bout) {
  int o = idx / K, k = idx - o * K;
  float scale = 1.0f, shift = 0.0f;
  if (bn != nullptr) {
    float g = bn[o], be = bn[NOUT + o], m = bn[2 * NOUT + o], v = bn[3 * NOUT + o];
    scale = g * rsqrtf(v + BN_EPS);
    shift = be - m * scale;
  }
  int gt = o >> 4, lr = o & 15, ks = k >> 5, lk = (k >> 3) & 3, e = k & 7;
  size_t pos = ((((size_t)gt * (K / 32) + ks) * 64) + lk * 16 + lr) * 8 + e;
  Wp[pos] = f2bf(W[(size_t)k * NOUT + o] * scale);
  if (k == 0) bout[o] = b[o] * scale + shift;
}

__device__ __forceinline__ void fold_f32_one(const float* __restrict__ W,
                                             const float* __restrict__ b,
                                             const float* __restrict__ bn,
                                             int K, int NOUT, int idx,
                                             float* __restrict__ Wt,
                                             float* __restrict__ bout) {
  int o = idx / K, k = idx - o * K;
  float scale = 1.0f, shift = 0.0f;
  if (bn != nullptr) {
    float g = bn[o], be = bn[NOUT + o], m = bn[2 * NOUT + o], v = bn[3 * NOUT + o];
    scale = g * rsqrtf(v + BN_EPS);
    shift = be - m * scale;
  }
  Wt[(size_t)o * K + k] = W[(size_t)k * NOUT + o] * scale;
  if (k == 0) bout[o] = b[o] * scale + shift;
}

__global__ __launch_bounds__(256) void fold_all_kernel(
    const float* __restrict__ in_W, const float* __restrict__ in_b, const float* __restrict__ in_bn,
    const float* __restrict__ W1, const float* __restrict__ b1, const float* __restrict__ bn1,
    const float* __restrict__ W2, const float* __restrict__ b2, const float* __restrict__ bn2,
    const float* __restrict__ W3, const float* __restrict__ b3, const float* __restrict__ nbn,
    const float* __restrict__ cW1, const float* __restrict__ cb1, const float* __restrict__ cbn1,
    const float* __restrict__ cW2, const float* __restrict__ cb2, const float* __restrict__ cbn2,
    const float* __restrict__ fW, const float* __restrict__ fb,
    ushort* __restrict__ wIn, float* __restrict__ bIn,
    ushort* __restrict__ w1f, float* __restrict__ b1f,
    ushort* __restrict__ w2f, float* __restrict__ b2f,
    ushort* __restrict__ w3f, float* __restrict__ b3f,
    float* __restrict__ cw1f, float* __restrict__ cb1f,
    float* __restrict__ cw2f, float* __restrict__ cb2f,
    float* __restrict__ cw3f, float* __restrict__ cb3f) {
  int idx = blockIdx.x * 256 + threadIdx.x;
  if (idx < 16384) {
    fold_pack_one(in_W, in_b, in_bn, 128, 128, idx, wIn, bIn);
    return;
  }
  idx -= 16384;
  if (idx < 5 * 180224) {
    int layer = idx / 180224;
    int r = idx - layer * 180224;
    if (r < 49152) {
      fold_pack_one(W1 + (size_t)layer * 49152, b1 + (size_t)layer * 384,
                    bn1 + (size_t)layer * 4 * 384, 128, 384, r,
                    w1f + (size_t)layer * 49152, b1f + (size_t)layer * 384);
    } else if (r < 147456) {
      fold_pack_one(W2 + (size_t)layer * 98304, b2 + (size_t)layer * 256,
                    bn2 + (size_t)layer * 4 * 256, 384, 256, r - 49152,
                    w2f + (size_t)layer * 98304, b2f + (size_t)layer * 256);
    } else {
      fold_pack_one(W3 + (size_t)layer * 32768, b3 + (size_t)layer * 128,
                    nbn + (size_t)layer * 4 * 128, 256, 128, r - 147456,
                    w3f + (size_t)layer * 32768, b3f + (size_t)layer * 128);
    }
    return;
  }
  idx -= 5 * 180224;
  if (idx < 49152) { fold_f32_one(cW1, cb1, cbn1, 384, 128, idx, cw1f, cb1f); return; }
  idx -= 49152;
  if (idx < 8192)  { fold_f32_one(cW2, cb2, cbn2, 128, 64, idx, cw2f, cb2f); return; }
  idx -= 8192;
  if (idx < 384)   { fold_f32_one(fW, fb, nullptr, 64, 6, idx, cw3f, cb3f); return; }
}

// ---------------- fp32 -> bf16 convert (x) ----------------
__global__ void cvt4_kernel(const float* __restrict__ x, ushort* __restrict__ xb, int n4) {
  int i = blockIdx.x * blockDim.x + threadIdx.x;
  if (i >= n4) return;
  float4 v = ((const float4*)x)[i];
  ushort4 o; o.x = f2bf(v.x); o.y = f2bf(v.y); o.z = f2bf(v.z); o.w = f2bf(v.w);
  ((ushort4*)xb)[i] = o;
}

// ---------------- CSR build: fused degree-hist (atomics) + graph bounds ---------------
__global__ void hist_gbound_kernel(const int* __restrict__ dst, int E,
                                   int* __restrict__ cnt,
                                   const int* __restrict__ batch, int N, int G,
                                   int* __restrict__ gptr) {
  int i = blockIdx.x * blockDim.x + threadIdx.x;
  if (i < E) atomicAdd(&cnt[dst[i]], 1);
  if (i < N) {
    int b = batch[i];
    int prev = (i == 0) ? -1 : batch[i - 1];
    for (int g = prev + 1; g <= b; ++g) gptr[g] = i;
    if (i == N - 1) for (int g = b + 1; g <= G; ++g) gptr[g] = N;
  }
}

__global__ void block_sum_kernel(const int* __restrict__ v, int n, int* __restrict__ bsum) {
  __shared__ int s[256];
  int i = blockIdx.x * 256 + threadIdx.x;
  int x = (i < n) ? v[i] : 0;
  s[threadIdx.x] = x; __syncthreads();
  for (int off = 128; off > 0; off >>= 1) {
    if (threadIdx.x < (unsigned)off) s[threadIdx.x] += s[threadIdx.x + off];
    __syncthreads();
  }
  if (threadIdx.x == 0) bsum[blockIdx.x] = s[0];
}

__global__ void scan_block_kernel(int* __restrict__ bsum, int nb,
                                  int* __restrict__ last_out, int total) {
  __shared__ int s[256];
  __shared__ int carry;
  if (threadIdx.x == 0) carry = 0;
  __syncthreads();
  for (int base = 0; base < nb; base += 256) {
    int i = base + threadIdx.x;
    int x = (i < nb) ? bsum[i] : 0;
    s[threadIdx.x] = x; __syncthreads();
    for (int off = 1; off < 256; off <<= 1) {
      int add = (threadIdx.x >= (unsigned)off) ? s[threadIdx.x - off] : 0;
      __syncthreads();
      s[threadIdx.x] += add;
      __syncthreads();
    }
    if (i < nb) bsum[i] = carry + s[threadIdx.x] - x;   // exclusive
    __syncthreads();
    if (threadIdx.x == 0) carry += s[255];
    __syncthreads();
  }
  if (last_out && threadIdx.x == 0) *last_out = total;
}

__global__ void scan_final_kernel(const int* __restrict__ v, int n, const int* __restrict__ bsum,
                                  int* __restrict__ rowptr, int* __restrict__ cursor) {
  __shared__ int s[256];
  int i = blockIdx.x * 256 + threadIdx.x;
  int x = (i < n) ? v[i] : 0;
  s[threadIdx.x] = x; __syncthreads();
  for (int off = 1; off < 256; off <<= 1) {
    int add = (threadIdx.x >= (unsigned)off) ? s[threadIdx.x - off] : 0;
    __syncthreads();
    s[threadIdx.x] += add;
    __syncthreads();
  }
  if (i < n) {
    int excl = bsum[blockIdx.x] + s[threadIdx.x] - x;
    rowptr[i] = excl;
    if (cursor) cursor[i] = excl;
  }
}

// dst-range-partitioned scatter (round-15 proven; plain cached loads — round-17 showed
// nontemporal loads net-regress: FETCH +16MB outweighs WRITE -11MB)
__global__ __launch_bounds__(256) void scatter_part_kernel(
    const int* __restrict__ src, const int* __restrict__ dst, int E,
    int* __restrict__ cursor, int* __restrict__ col, int npp) {
  const int part  = blockIdx.x & 7;
  const int chunk = blockIdx.x >> 3;
  const int lo = part * npp, hi = lo + npp;
  const int i0 = chunk * 1024 + threadIdx.x * 4;
  if (i0 + 3 < E) {
    int4 d4 = *(const int4*)(dst + i0);
    if (d4.x >= lo && d4.x < hi) { int p = atomicAdd(&cursor[d4.x], 1); col[p] = src[i0 + 0]; }
    if (d4.y >= lo && d4.y < hi) { int p = atomicAdd(&cursor[d4.y], 1); col[p] = src[i0 + 1]; }
    if (d4.z >= lo && d4.z < hi) { int p = atomicAdd(&cursor[d4.z], 1); col[p] = src[i0 + 2]; }
    if (d4.w >= lo && d4.w < hi) { int p = atomicAdd(&cursor[d4.w], 1); col[p] = src[i0 + 3]; }
  } else {
    for (int u = 0; u < 4; ++u) {
      int i = i0 + u;
      if (i < E) {
        int d = dst[i];
        if (d >= lo && d < hi) { int p = atomicAdd(&cursor[d], 1); col[p] = src[i]; }
      }
    }
  }
}

// ---------------- GIN aggregation (round-12 proven: 4-deep gather unroll) --------------
__global__ __launch_bounds__(256) void agg_kernel(
    const ushort* __restrict__ hb,
    const int* __restrict__ rowptr, const int* __restrict__ col,
    const float* __restrict__ eps_g, int layer,
    ushort* __restrict__ z, int n) {
  int node = blockIdx.x * 4 + (threadIdx.x >> 6);
  if (node >= n) return;
  const int lane = threadIdx.x & 63;
  const int l16  = lane & 15;
  const int grp  = lane >> 4;
  const int s = rowptr[node], e = rowptr[node + 1];
  float a0 = 0.f, a1 = 0.f, a2 = 0.f, a3 = 0.f, a4 = 0.f, a5 = 0.f, a6 = 0.f, a7 = 0.f;
  const size_t co = (size_t)l16 * 8;
  int j = s + grp;
  for (; j + 12 < e; j += 16) {
    int i0 = col[j], i1 = col[j + 4], i2 = col[j + 8], i3 = col[j + 12];
    bf16x8 v0 = *(const bf16x8*)(hb + (size_t)i0 * H + co);
    bf16x8 v1 = *(const bf16x8*)(hb + (size_t)i1 * H + co);
    bf16x8 v2 = *(const bf16x8*)(hb + (size_t)i2 * H + co);
    bf16x8 v3 = *(const bf16x8*)(hb + (size_t)i3 * H + co);
    a0 += (bf2f((ushort)v0[0]) + bf2f((ushort)v1[0])) + (bf2f((ushort)v2[0]) + bf2f((ushort)v3[0]));
    a1 += (bf2f((ushort)v0[1]) + bf2f((ushort)v1[1])) + (bf2f((ushort)v2[1]) + bf2f((ushort)v3[1]));
    a2 += (bf2f((ushort)v0[2]) + bf2f((ushort)v1[2])) + (bf2f((ushort)v2[2]) + bf2f((ushort)v3[2]));
    a3 += (bf2f((ushort)v0[3]) + bf2f((ushort)v1[3])) + (bf2f((ushort)v2[3]) + bf2f((ushort)v3[3]));
    a4 += (bf2f((ushort)v0[4]) + bf2f((ushort)v1[4])) + (bf2f((ushort)v2[4]) + bf2f((ushort)v3[4]));
    a5 += (bf2f((ushort)v0[5]) + bf2f((ushort)v1[5])) + (bf2f((ushort)v2[5]) + bf2f((ushort)v3[5]));
    a6 += (bf2f((ushort)v0[6]) + bf2f((ushort)v1[6])) + (bf2f((ushort)v2[6]) + bf2f((ushort)v3[6]));
    a7 += (bf2f((ushort)v0[7]) + bf2f((ushort)v1[7])) + (bf2f((ushort)v2[7]) + bf2f((ushort)v3[7]));
  }
  for (; j + 4 < e; j += 8) {
    int i0 = col[j], i1 = col[j + 4];
    bf16x8 v0 = *(const bf16x8*)(hb + (size_t)i0 * H + co);
    bf16x8 v1 = *(const bf16x8*)(hb + (size_t)i1 * H + co);
    a0 += bf2f((ushort)v0[0]) + bf2f((ushort)v1[0]);
    a1 += bf2f((ushort)v0[1]) + bf2f((ushort)v1[1]);
    a2 += bf2f((ushort)v0[2]) + bf2f((ushort)v1[2]);
    a3 += bf2f((ushort)v0[3]) + bf2f((ushort)v1[3]);
    a4 += bf2f((ushort)v0[4]) + bf2f((ushort)v1[4]);
    a5 += bf2f((ushort)v0[5]) + bf2f((ushort)v1[5]);
    a6 += bf2f((ushort)v0[6]) + bf2f((ushort)v1[6]);
    a7 += bf2f((ushort)v0[7]) + bf2f((ushort)v1[7]);
  }
  if (j < e) {
    bf16x8 v0 = *(const bf16x8*)(hb + (size_t)col[j] * H + co);
    a0 += bf2f((ushort)v0[0]); a1 += bf2f((ushort)v0[1]);
    a2 += bf2f((ushort)v0[2]); a3 += bf2f((ushort)v0[3]);
    a4 += bf2f((ushort)v0[4]); a5 += bf2f((ushort)v0[5]);
    a6 += bf2f((ushort)v0[6]); a7 += bf2f((ushort)v0[7]);
  }
  a0 += __shfl_xor(a0, 16); a0 += __shfl_xor(a0, 32);
  a1 += __shfl_xor(a1, 16); a1 += __shfl_xor(a1, 32);
  a2 += __shfl_xor(a2, 16); a2 += __shfl_xor(a2, 32);
  a3 += __shfl_xor(a3, 16); a3 += __shfl_xor(a3, 32);
  a4 += __shfl_xor(a4, 16); a4 += __shfl_xor(a4, 32);
  a5 += __shfl_xor(a5, 16); a5 += __shfl_xor(a5, 32);
  a6 += __shfl_xor(a6, 16); a6 += __shfl_xor(a6, 32);
  a7 += __shfl_xor(a7, 16); a7 += __shfl_xor(a7, 32);
  float sx, sy;
  if      (grp == 0) { sx = a0; sy = a1; }
  else if (grp == 1) { sx = a2; sy = a3; }
  else if (grp == 2) { sx = a4; sy = a5; }
  else               { sx = a6; sy = a7; }
  const int c0 = l16 * 8 + grp * 2;
  float ep = 1.0f + eps_g[layer];
  ushort2 hs = *(const ushort2*)(hb + (size_t)node * H + c0);
  ushort2 o;
  o.x = f2bf(ep * bf2f(hs.x) + sx);
  o.y = f2bf(ep * bf2f(hs.y) + sy);
  *(ushort2*)(z + (size_t)node * H + c0) = o;
}

// ---------------- input projection GEMM (M=64, packed weights) ----------------
template<int K, int NOUT>
__global__ __launch_bounds__(256) void gemm_kernel(
    const ushort* __restrict__ A, const ushort* __restrict__ Wp,
    const float* __restrict__ bias,
    ushort* __restrict__ outb, float* __restrict__ hf) {
  constexpr int ROWB = 2 * K;
  __shared__ __align__(16) char lds[64 * ROWB];
  const int t = threadIdx.x;
  const long row0 = (long)blockIdx.x * 64;
  const char* Ab = (const char*)(A + (size_t)row0 * K);

  constexpr int ITERS = (64 * ROWB) / (256 * 16);
#pragma unroll
  for (int it = 0; it < ITERS; ++it) {
    int ob = (it * 256 + t) * 16;
    int r = ob / ROWB;
    int c = ob - r * ROWB;
    int sb = r * ROWB + (c ^ ((r & 7) << 4));
    __builtin_amdgcn_global_load_lds((const GLOBAL_AS void*)(Ab + sb),
                                     (LDS_AS void*)(lds + ob), 16, 0, 0);
  }
  __syncthreads();

  const int l  = t & 63;
  const int w  = t >> 6;
  const int lr = l & 15;
  const int lk = l >> 4;
  constexpr int CPW = NOUT / 4;
  constexpr int NCT = CPW / 16;

  for (int ct = 0; ct < NCT; ++ct) {
    const int colbase = w * CPW + ct * 16;
    const ushort* tb = Wp + ((size_t)(colbase >> 4) * (K / 32)) * 512;
    f32x4 acc[4] = {};
#pragma unroll
    for (int ks = 0; ks < K / 32; ++ks) {
      bf16x8 bfr = *(const bf16x8*)(tb + ks * 512 + l * 8);
#pragma unroll
      for (int rt = 0; rt < 4; ++rt) {
        const int rr = rt * 16 + lr;
        const int kb = ks * 64 + lk * 16;
        bf16x8 afr = *(const bf16x8*)(lds + rr * ROWB + (kb ^ ((rr & 7) << 4)));
        acc[rt] = __builtin_amdgcn_mfma_f32_16x16x32_bf16(bfr, afr, acc[rt], 0, 0, 0);
      }
    }
    const int c0 = colbase + lk * 4;
    const float b0 = bias[c0], b1 = bias[c0 + 1], b2 = bias[c0 + 2], b3 = bias[c0 + 3];
#pragma unroll
    for (int rt = 0; rt < 4; ++rt) {
      const long grow = row0 + rt * 16 + lr;
      float v0 = fmaxf(acc[rt][0] + b0, 0.f);
      float v1 = fmaxf(acc[rt][1] + b1, 0.f);
      float v2 = fmaxf(acc[rt][2] + b2, 0.f);
      float v3 = fmaxf(acc[rt][3] + b3, 0.f);
      *(float4*)(hf + grow * H + c0) = make_float4(v0, v1, v2, v3);
      ushort4 sv; sv.x = f2bf(v0); sv.y = f2bf(v1); sv.z = f2bf(v2); sv.w = f2bf(v3);
      *(ushort4*)(outb + grow * NOUT + c0) = sv;
    }
  }
}

// ---------------- fused per-layer MLP (round-14 proven; M=64, 512 thr, 64KB LDS) ------
template<int HMODE>  // 1: write h (no residual), 2: h += old
__global__ __launch_bounds__(512, 4) void mlp_fused_kernel(
    const ushort* __restrict__ zin,
    const ushort* __restrict__ w1, const float* __restrict__ bb1,
    const ushort* __restrict__ w2, const float* __restrict__ bb2,
    const ushort* __restrict__ w3, const float* __restrict__ bb3,
    ushort* __restrict__ hb, float* __restrict__ hf) {
  __shared__ __align__(16) char lds[64 * 1024];
  char* t1 = lds;               // [64][768B]
  char* zz = lds + 48 * 1024;   // [64][256B]
  char* t2 = lds + 32 * 1024;   // [64][512B], overlays t1-top + zz after stage-2 reads

  const int t = threadIdx.x;
  const long row0 = (long)blockIdx.x * 64;
  const char* Ab = (const char*)(zin + (size_t)row0 * 128);

#pragma unroll
  for (int it = 0; it < 2; ++it) {
    int ob = (it * 512 + t) * 16;
    int r = ob >> 8;
    int c = ob & 255;
    int sb = r * 256 + (c ^ ((r & 7) << 4));
    __builtin_amdgcn_global_load_lds((const GLOBAL_AS void*)(Ab + sb),
                                     (LDS_AS void*)(zz + ob), 16, 0, 0);
  }
  __syncthreads();

  const int l  = t & 63;
  const int w  = t >> 6;    // 0..7
  const int lr = l & 15;
  const int lk = l >> 4;

  // ---- stage 1: wave cols [w*48,+48) = 3 tiles, rows 0..63
  {
    f32x4 acc[3][4] = {};
#pragma unroll
    for (int ks = 0; ks < 4; ++ks) {
      bf16x8 afr[4];
#pragma unroll
      for (int rt = 0; rt < 4; ++rt) {
        const int rr = rt * 16 + lr;
        afr[rt] = *(const bf16x8*)(zz + rr * 256 + ((ks * 64 + lk * 16) ^ ((rr & 7) << 4)));
      }
#pragma unroll
      for (int ct = 0; ct < 3; ++ct) {
        bf16x8 bfr = *(const bf16x8*)(w1 + ((size_t)(w * 3 + ct) * 4 + ks) * 512 + l * 8);
#pragma unroll
        for (int rt = 0; rt < 4; ++rt)
          acc[ct][rt] = __builtin_amdgcn_mfma_f32_16x16x32_bf16(bfr, afr[rt], acc[ct][rt], 0, 0, 0);
      }
    }
#pragma unroll
    for (int ct = 0; ct < 3; ++ct) {
      const int c0 = w * 48 + ct * 16 + lk * 4;
      const float b0 = bb1[c0], b1 = bb1[c0 + 1], b2 = bb1[c0 + 2], b3 = bb1[c0 + 3];
#pragma unroll
      for (int rt = 0; rt < 4; ++rt) {
        const int rr = rt * 16 + lr;
        ushort4 sv;
        sv.x = f2bf(fmaxf(acc[ct][rt][0] + b0, 0.f));
        sv.y = f2bf(fmaxf(acc[ct][rt][1] + b1, 0.f));
        sv.z = f2bf(fmaxf(acc[ct][rt][2] + b2, 0.f));
        sv.w = f2bf(fmaxf(acc[ct][rt][3] + b3, 0.f));
        *(ushort4*)(t1 + rr * 768 + ((c0 * 2) ^ ((rr & 7) << 4))) = sv;
      }
    }
  }
  __syncthreads();

  // ---- stage 2: wave cols [w*32,+32) = 2 tiles, K=384
  {
    f32x4 acc[2][4] = {};
#pragma unroll
    for (int ks = 0; ks < 12; ++ks) {
      bf16x8 afr[4];
#pragma unroll
      for (int rt = 0; rt < 4; ++rt) {
        const int rr = rt * 16 + lr;
        afr[rt] = *(const bf16x8*)(t1 + rr * 768 + ((ks * 64 + lk * 16) ^ ((rr & 7) << 4)));
      }
#pragma unroll
      for (int ct = 0; ct < 2; ++ct) {
        bf16x8 bfr = *(const bf16x8*)(w2 + ((size_t)(w * 2 + ct) * 12 + ks) * 512 + l * 8);
#pragma unroll
        for (int rt = 0; rt < 4; ++rt)
          acc[ct][rt] = __builtin_amdgcn_mfma_f32_16x16x32_bf16(bfr, afr[rt], acc[ct][rt], 0, 0, 0);
      }
    }
    __syncthreads();   // ALL t1/zz reads done; t2 may overlay [32K,64K)
#pragma unroll
    for (int ct = 0; ct < 2; ++ct) {
      const int c0 = w * 32 + ct * 16 + lk * 4;
      const float b0 = bb2[c0], b1 = bb2[c0 + 1], b2 = bb2[c0 + 2], b3 = bb2[c0 + 3];
#pragma unroll
      for (int rt = 0; rt < 4; ++rt) {
        const int rr = rt * 16 + lr;
        ushort4 sv;
        sv.x = f2bf(fmaxf(acc[ct][rt][0] + b0, 0.f));
        sv.y = f2bf(fmaxf(acc[ct][rt][1] + b1, 0.f));
        sv.z = f2bf(fmaxf(acc[ct][rt][2] + b2, 0.f));
        sv.w = f2bf(fmaxf(acc[ct][rt][3] + b3, 0.f));
        *(ushort4*)(t2 + rr * 512 + ((c0 * 2) ^ ((rr & 7) << 4))) = sv;
      }
    }
  }
  __syncthreads();

  // ---- stage 3: wave cols [w*16,+16) = 1 tile
  {
    f32x4 acc[4] = {};
#pragma unroll
    for (int ks = 0; ks < 8; ++ks) {
      bf16x8 afr[4];
#pragma unroll
      for (int rt = 0; rt < 4; ++rt) {
        const int rr = rt * 16 + lr;
        afr[rt] = *(const bf16x8*)(t2 + rr * 512 + ((ks * 64 + lk * 16) ^ ((rr & 7) << 4)));
      }
      bf16x8 bfr = *(const bf16x8*)(w3 + ((size_t)w * 8 + ks) * 512 + l * 8);
#pragma unroll
      for (int rt = 0; rt < 4; ++rt)
        acc[rt] = __builtin_amdgcn_mfma_f32_16x16x32_bf16(bfr, afr[rt], acc[rt], 0, 0, 0);
    }
    const int c0 = w * 16 + lk * 4;
    const float b0 = bb3[c0], b1 = bb3[c0 + 1], b2 = bb3[c0 + 2], b3v = bb3[c0 + 3];
#pragma unroll
    for (int rt = 0; rt < 4; ++rt) {
      const long grow = row0 + rt * 16 + lr;
      float v0 = fmaxf(acc[rt][0] + b0, 0.f);
      float v1 = fmaxf(acc[rt][1] + b1, 0.f);
      float v2 = fmaxf(acc[rt][2] + b2, 0.f);
      float v3 = fmaxf(acc[rt][3] + b3v, 0.f);
      float4* hp = (float4*)(hf + grow * H + c0);
      if (HMODE == 2) {
        float4 o = *hp;
        v0 += o.x; v1 += o.y; v2 += o.z; v3 += o.w;
      }
      *hp = make_float4(v0, v1, v2, v3);
      ushort4 sv; sv.x = f2bf(v0); sv.y = f2bf(v1); sv.z = f2bf(v2); sv.w = f2bf(v3);
      *(ushort4*)(hb + grow * H + c0) = sv;
    }
  }
}

// ---------------- readout: sum / mean / max per graph (round-15 proven) ----------------
__global__ __launch_bounds__(1024) void readout_kernel(const float* __restrict__ hf,
                                                       const int* __restrict__ gptr,
                                                       float* __restrict__ g) {
  __shared__ float ssum[8][128];
  __shared__ float smax[8][128];
  const int gi  = blockIdx.x;
  const int t   = threadIdx.x;
  const int grp = t >> 7;      // 0..7
  const int c   = t & 127;
  const int s = gptr[gi], e = gptr[gi + 1];
  float sum = 0.f, mx = -INFINITY;
  for (int n = s + grp; n < e; n += 8) {
    float v = hf[(size_t)n * H + c];
    sum += v; mx = fmaxf(mx, v);
  }
  ssum[grp][c] = sum;
  smax[grp][c] = mx;
  __syncthreads();
  if (t < 128) {
    float s0 = 0.f, m0 = -INFINITY;
#pragma unroll
    for (int k = 0; k < 8; ++k) { s0 += ssum[k][t]; m0 = fmaxf(m0, smax[k][t]); }
    const int cnt = e - s;
    g[gi * 384 + t]       = s0;
    g[gi * 384 + 128 + t] = s0 / fmaxf((float)cnt, 1.f);
    g[gi * 384 + 256 + t] = (cnt > 0) ? m0 : 0.f;
  }
}

// ---------------- classifier head ----------------
__global__ __launch_bounds__(128) void classifier_kernel(
    const float* __restrict__ g,
    const float* __restrict__ W1, const float* __restrict__ b1,
    const float* __restrict__ W2, const float* __restrict__ b2,
    const float* __restrict__ W3, const float* __restrict__ b3,
    float* __restrict__ out) {
  __shared__ float row[384];
  __shared__ float f1[128];
  __shared__ float f2s[64];
  int gi = blockIdx.x, t = threadIdx.x;
  for (int i = t; i < 384; i += 128) row[i] = g[gi * 384 + i];
  __syncthreads();
  float a = b1[t];
  for (int k = 0; k < 384; ++k) a += row[k] * W1[t * 384 + k];
  f1[t] = fmaxf(a, 0.f);
  __syncthreads();
  if (t < 64) {
    float a2 = b2[t];
    for (int k = 0; k < 128; ++k) a2 += f1[k] * W2[t * 128 + k];
    f2s[t] = fmaxf(a2, 0.f);
  }
  __syncthreads();
  if (t < 6) {
    float a3 = b3[t];
    for (int k = 0; k < 64; ++k) a3 += f2s[k] * W3[t * 64 + k];
    out[gi * 6 + t] = a3;
  }
}

// ---------------- launcher ----------------
extern "C" void kernel_launch(void* const* d_in, const int* in_sizes, int n_in,
                              void* d_out, int out_size, void* d_ws, size_t ws_size,
                              hipStream_t stream) {
  (void)n_in; (void)ws_size;
  const float* x     = (const float*)d_in[0];
  const int*   eidx  = (const int*)d_in[1];
  const int*   batch = (const int*)d_in[2];
  const float* in_W  = (const float*)d_in[3];
  const float* in_b  = (const float*)d_in[4];
  const float* in_bn = (const float*)d_in[5];
  const float* W1    = (const float*)d_in[6];
  const float* b1    = (const float*)d_in[7];
  const float* bn1   = (const float*)d_in[8];
  const float* W2    = (const float*)d_in[9];
  const float* b2    = (const float*)d_in[10];
  const float* bn2   = (const float*)d_in[11];
  const float* W3    = (const float*)d_in[12];
  const float* b3    = (const float*)d_in[13];
  const float* eps_g = (const float*)d_in[14];
  const float* nbn   = (const float*)d_in[15];
  const float* cW1   = (const float*)d_in[16];
  const float* cb1   = (const float*)d_in[17];
  const float* cbn1  = (const float*)d_in[18];
  const float* cW2   = (const float*)d_in[19];
  const float* cb2   = (const float*)d_in[20];
  const float* cbn2  = (const float*)d_in[21];
  const float* fW    = (const float*)d_in[22];
  const float* fb    = (const float*)d_in[23];

  const int N  = in_sizes[0] / 128;
  const int E  = in_sizes[1] / 2;
  const int G  = out_size / 6;
  const int Mp = ((N + 63) / 64) * 64;
  const int gblocks = Mp / 64;            // input projection + fused MLP (M=64)
  const int npp = (N + 7) / 8;            // nodes per scatter partition
  const int nchunks = (E + 1023) / 1024;  // edge chunks of 1024

  char* p = (char*)d_ws;
  auto alloc = [&](size_t bytes) -> char* {
    char* r = p; p += (bytes + 255) & ~(size_t)255; return r;
  };
  ushort* hb     = (ushort*)alloc((size_t)Mp * H * 2);
  ushort* zb     = (ushort*)alloc((size_t)Mp * H * 2);
  ushort* xb     = (ushort*)alloc((size_t)Mp * H * 2);
  float*  hf     = (float*)alloc((size_t)Mp * H * 4);
  int*    deg    = (int*)alloc((size_t)N * 4);
  int*    rowptr = (int*)alloc((size_t)(N + 1) * 4);
  int*    cursor = (int*)alloc((size_t)N * 4);
  int*    colx   = (int*)alloc((size_t)E * 4);
  int*    bsum   = (int*)alloc(4096);
  int*    gptr   = (int*)alloc((size_t)(G + 1) * 4);
  float*  gbuf   = (float*)alloc((size_t)G * 384 * 4);
  ushort* wIn    = (ushort*)alloc(128 * 128 * 2);
  float*  bIn    = (float*)alloc(128 * 4);
  ushort* w1f    = (ushort*)alloc((size_t)5 * 384 * 128 * 2);
  float*  b1f    = (float*)alloc((size_t)5 * 384 * 4);
  ushort* w2f    = (ushort*)alloc((size_t)5 * 256 * 384 * 2);
  float*  b2f    = (float*)alloc((size_t)5 * 256 * 4);
  ushort* w3f    = (ushort*)alloc((size_t)5 * 128 * 256 * 2);
  float*  b3f    = (float*)alloc((size_t)5 * 128 * 4);
  float*  cw1f   = (float*)alloc(128 * 384 * 4);
  float*  cb1f   = (float*)alloc(128 * 4);
  float*  cw2f   = (float*)alloc(64 * 128 * 4);
  float*  cb2f   = (float*)alloc(64 * 4);
  float*  cw3f   = (float*)alloc(6 * 64 * 4);
  float*  cb3f   = (float*)alloc(6 * 4);

  // ---- weight folding: ONE launch for all 22 matrices ----
  const int fold_total = 16384 + 5 * 180224 + 49152 + 8192 + 384;
  fold_all_kernel<<<(fold_total + 255) / 256, 256, 0, stream>>>(
      in_W, in_b, in_bn, W1, b1, bn1, W2, b2, bn2, W3, b3, nbn,
      cW1, cb1, cbn1, cW2, cb2, cbn2, fW, fb,
      wIn, bIn, w1f, b1f, w2f, b2f, w3f, b3f,
      cw1f, cb1f, cw2f, cb2f, cw3f, cb3f);

  // ---- x -> bf16 ----
  cvt4_kernel<<<(N * 128 / 4 + 255) / 256, 256, 0, stream>>>(x, xb, N * 128 / 4);

  // ---- CSR build + graph ranges ----
  hipMemsetAsync(deg, 0, (size_t)N * 4, stream);
  const int hgb = ((E > N ? E : N) + 255) / 256;
  hist_gbound_kernel<<<hgb, 256, 0, stream>>>(eidx + E, E, deg, batch, N, G, gptr);
  const int nb = (N + 255) / 256;
  block_sum_kernel<<<nb, 256, 0, stream>>>(deg, N, bsum);
  scan_block_kernel<<<1, 256, 0, stream>>>(bsum, nb, rowptr + N, E);
  scan_final_kernel<<<nb, 256, 0, stream>>>(deg, N, bsum, rowptr, cursor);
  scatter_part_kernel<<<nchunks * 8, 256, 0, stream>>>(eidx, eidx + E, E, cursor, colx, npp);

  // ---- input projection ----
  gemm_kernel<128, 128><<<gblocks, 256, 0, stream>>>(xb, wIn, bIn, hb, hf);

  // ---- GIN layers ----
  for (int i = 0; i < 5; ++i) {
    agg_kernel<<<(N + 3) / 4, 256, 0, stream>>>(hb, rowptr, colx, eps_g, i, zb, N);
    if (i == 0)
      mlp_fused_kernel<1><<<gblocks, 512, 0, stream>>>(
          zb, w1f + (size_t)i * 384 * 128, b1f + (size_t)i * 384,
          w2f + (size_t)i * 256 * 384, b2f + (size_t)i * 256,
          w3f + (size_t)i * 128 * 256, b3f + (size_t)i * 128, hb, hf);
    else
      mlp_fused_kernel<2><<<gblocks, 512, 0, stream>>>(
          zb, w1f + (size_t)i * 384 * 128, b1f + (size_t)i * 384,
          w2f + (size_t)i * 256 * 384, b2f + (size_t)i * 256,
          w3f + (size_t)i * 128 * 256, b3f + (size_t)i * 128, hb, hf);
  }

  // ---- readout + classifier ----
  readout_kernel<<<G, 1024, 0, stream>>>(hf, gptr, gbuf);
  classifier_kernel<<<G, 128, 0, stream>>>(gbuf, cw1f, cb1f, cw2f, cb2f, cw3f, cb3f,
                                           (float*)d_out);
}